// Round 3
// baseline (1582.729 us; speedup 1.0000x reference)
//
#include <hip/hip_runtime.h>
#include <hip/hip_bf16.h>

typedef __bf16 bf16_t;
typedef __bf16 bf16x8 __attribute__((ext_vector_type(8)));
typedef __bf16 bf16x4 __attribute__((ext_vector_type(4)));
typedef float  f32x4  __attribute__((ext_vector_type(4)));

// async global->LDS, 16B per lane. LDS dest = wave-uniform base + lane*16.
__device__ __forceinline__ void gl_lds16(const void* g, void* l) {
    __builtin_amdgcn_global_load_lds(
        (__attribute__((address_space(1))) void*)g,
        (__attribute__((address_space(3))) void*)l, 16, 0, 0);
}

template <int N>
__device__ __forceinline__ void wait_vm() {
    if constexpr (N == 0)      asm volatile("s_waitcnt vmcnt(0)" ::: "memory");
    else if constexpr (N == 3) asm volatile("s_waitcnt vmcnt(3)" ::: "memory");
    else                       asm volatile("s_waitcnt vmcnt(4)" ::: "memory");
}

// ---------------------------------------------------------------------------
// fp32 -> bf16 cast, vectorized (n must be multiple of 4)
// ---------------------------------------------------------------------------
__global__ void cvt_kernel(const float* __restrict__ in, bf16_t* __restrict__ out,
                           int n4) {
    const int i = blockIdx.x * 256 + threadIdx.x;
    if (i < n4) {
        const float4 v = ((const float4*)in)[i];
        bf16x4 o;
        o.x = (bf16_t)v.x; o.y = (bf16_t)v.y; o.z = (bf16_t)v.z; o.w = (bf16_t)v.w;
        ((bf16x4*)out)[i] = o;
    }
}

// 4 segments in one launch (per-layer weight casts)
__global__ void cvt4_kernel(const float* __restrict__ s0, const float* __restrict__ s1,
                            const float* __restrict__ s2, const float* __restrict__ s3,
                            bf16_t* __restrict__ d0, bf16_t* __restrict__ d1,
                            bf16_t* __restrict__ d2, bf16_t* __restrict__ d3,
                            int n0, int n1, int n2, int n3) {
    int j = blockIdx.x * 256 + threadIdx.x;
    const float* s; bf16_t* d;
    if (j < n0) { s = s0; d = d0; }
    else {
        j -= n0;
        if (j < n1) { s = s1; d = d1; }
        else {
            j -= n1;
            if (j < n2) { s = s2; d = d2; }
            else {
                j -= n2;
                if (j >= n3) return;
                s = s3; d = d3;
            }
        }
    }
    const float4 v = ((const float4*)s)[j];
    bf16x4 o;
    o.x = (bf16_t)v.x; o.y = (bf16_t)v.y; o.z = (bf16_t)v.z; o.w = (bf16_t)v.w;
    ((bf16x4*)d)[j] = o;
}

// ---------------------------------------------------------------------------
// RoPE cos/sin table: tab[t*32+i] = {cos, sin}(t * 10000^(-i/32))
// ---------------------------------------------------------------------------
__global__ void rope_table(float* __restrict__ tab) {
    const int i = blockIdx.x * 256 + threadIdx.x;   // T*32 items
    const int t = i >> 5, f = i & 31;
    const float inv_freq = __powf(10000.0f, -(float)f * (1.0f / 32.0f));
    const float ang = (float)t * inv_freq;
    float s, c;
    __sincosf(ang, &s, &c);
    tab[2 * i]     = c;
    tab[2 * i + 1] = s;
}

// ---------------------------------------------------------------------------
// Embedding gather: x[t,:] = wte[idx[t],:]  (fp32, float4)
// ---------------------------------------------------------------------------
__global__ void embed_kernel(const int* __restrict__ idx,
                             const float* __restrict__ wte,
                             float* __restrict__ x) {
    const int t = blockIdx.x;
    const int row = idx[t];
    const float4* w = (const float4*)(wte + (size_t)row * 768);
    float4* o = (float4*)(x + (size_t)t * 768);
    if (threadIdx.x < 192) o[threadIdx.x] = w[threadIdx.x];
}

// ---------------------------------------------------------------------------
// LayerNorm: out(bf16) = (x - mu) * rsqrt(var + eps) * w      D = 768
// ---------------------------------------------------------------------------
__global__ __launch_bounds__(256) void ln_kernel(const float* __restrict__ x,
                                                 const float* __restrict__ w,
                                                 bf16_t* __restrict__ out) {
    const int t = blockIdx.x, tid = threadIdx.x;
    __shared__ float red[256];
    const float* xr = x + (size_t)t * 768;
    const float v0 = xr[tid], v1 = xr[tid + 256], v2 = xr[tid + 512];
    red[tid] = v0 + v1 + v2;
    __syncthreads();
    for (int s = 128; s > 0; s >>= 1) {
        if (tid < s) red[tid] += red[tid + s];
        __syncthreads();
    }
    const float mu = red[0] * (1.0f / 768.0f);
    __syncthreads();
    const float d0 = v0 - mu, d1 = v1 - mu, d2 = v2 - mu;
    red[tid] = d0 * d0 + d1 * d1 + d2 * d2;
    __syncthreads();
    for (int s = 128; s > 0; s >>= 1) {
        if (tid < s) red[tid] += red[tid + s];
        __syncthreads();
    }
    const float rstd = rsqrtf(red[0] * (1.0f / 768.0f) + 1e-5f);
    bf16_t* orow = out + (size_t)t * 768;
    orow[tid]       = (bf16_t)(d0 * rstd * w[tid]);
    orow[tid + 256] = (bf16_t)(d1 * rstd * w[tid + 256]);
    orow[tid + 512] = (bf16_t)(d2 * rstd * w[tid + 512]);
}

// ---------------------------------------------------------------------------
// RoPE + bf16 pack + V transpose. grid (T/64, NH), block 256.
// ---------------------------------------------------------------------------
__global__ __launch_bounds__(256) void rope_prep(const float* __restrict__ qkv,
                                                 const float* __restrict__ tab,
                                                 bf16_t* __restrict__ Qb,
                                                 bf16_t* __restrict__ Kb,
                                                 bf16_t* __restrict__ Vt) {
    const int t0 = blockIdx.x * 64, h = blockIdx.y;
    const int tid = threadIdx.x;
    __shared__ bf16_t vt[64][65];   // [d][k], padded row

    #pragma unroll
    for (int it = 0; it < 16; ++it) {
        const int item = it * 256 + tid;
        const int tl = item >> 6;
        const int which = (item >> 5) & 1;   // 0 = Q, 1 = K
        const int i = item & 31;
        const float* src = qkv + (size_t)(t0 + tl) * 2304 + which * 768 + h * 64;
        const float2 cs = ((const float2*)tab)[(t0 + tl) * 32 + i];
        const float c = cs.x, s = cs.y;
        const float x1 = src[i], x2 = src[i + 32];
        bf16_t* dst = (which ? Kb : Qb) + ((size_t)h * 2048 + t0 + tl) * 64;
        const float sc = which ? 1.0f : 0.125f;   // fold attn scale into Q
        dst[i]      = (bf16_t)((x1 * c - x2 * s) * sc);
        dst[i + 32] = (bf16_t)((x1 * s + x2 * c) * sc);
    }

    #pragma unroll
    for (int pass = 0; pass < 4; ++pass) {
        const int r = pass * 16 + (tid >> 4);   // key row 0..63
        const int c = (tid & 15) * 4;           // d 0..60
        const float4 v = *(const float4*)(qkv + (size_t)(t0 + r) * 2304 + 1536 + h * 64 + c);
        vt[c + 0][r] = (bf16_t)v.x;
        vt[c + 1][r] = (bf16_t)v.y;
        vt[c + 2][r] = (bf16_t)v.z;
        vt[c + 3][r] = (bf16_t)v.w;
    }
    __syncthreads();
    #pragma unroll
    for (int pass = 0; pass < 2; ++pass) {
        const int d = pass * 32 + (tid >> 3);
        const int k8 = (tid & 7) * 8;
        bf16x8 vv;
        #pragma unroll
        for (int j = 0; j < 8; ++j) vv[j] = vt[d][k8 + j];
        *(bf16x8*)(Vt + ((size_t)h * 64 + d) * 2048 + t0 + k8) = vv;
    }
}

// ---------------------------------------------------------------------------
// MFMA flash attention. Block = (64-query tile, head), 256 threads (4 waves).
// ---------------------------------------------------------------------------
__global__ __launch_bounds__(256) void attn_mfma(const bf16_t* __restrict__ Qb,
                                                 const bf16_t* __restrict__ Kb,
                                                 const bf16_t* __restrict__ Vt,
                                                 bf16_t* __restrict__ y) {
    const int qt = (int)gridDim.x - 1 - (int)blockIdx.x;  // longest blocks first
    const int h  = blockIdx.y;
    const int q0 = qt * 64;
    const int tid = threadIdx.x;
    const int w = tid >> 6, lane = tid & 63;
    const int lg = lane >> 4;       // lane group 0..3
    const int ll = lane & 15;

    __shared__ bf16_t Ks[64 * 64];  // [key][d], swizzled
    __shared__ bf16_t Vs[64 * 64];  // [d][key] (V^T tile), swizzled
    __shared__ bf16_t Ps[64 * 64];  // [q][key], swizzled (per-wave private rows)

    bf16x8 aq0, aq1;
    {
        const bf16_t* qp = Qb + ((size_t)h * 2048 + q0 + w * 16 + ll) * 64 + lg * 8;
        aq0 = *(const bf16x8*)qp;
        aq1 = *(const bf16x8*)(qp + 32);
    }

    f32x4 o[4];
    #pragma unroll
    for (int i = 0; i < 4; ++i) o[i] = (f32x4)(0.0f);
    float m_i[4], l_i[4];
    #pragma unroll
    for (int r = 0; r < 4; ++r) { m_i[r] = -3e38f; l_i[r] = 0.0f; }

    const int srow0 = tid >> 3;          // rows 0..31
    const int srow1 = srow0 + 32;        // rows 32..63
    const int sc16  = tid & 7;           // 16B chunk within 128B row

    const bf16_t* Kbase = Kb + (size_t)h * 2048 * 64;
    const bf16_t* Vbase = Vt + (size_t)h * 64 * 2048;

    for (int kt = 0; kt <= qt; ++kt) {
        __syncthreads();
        {
            const bf16_t* kg = Kbase + (size_t)(kt * 64) * 64;
            const bf16x8 k0 = *(const bf16x8*)(kg + srow0 * 64 + sc16 * 8);
            const bf16x8 k1 = *(const bf16x8*)(kg + srow1 * 64 + sc16 * 8);
            const bf16_t* vg = Vbase + kt * 64;
            const bf16x8 v0 = *(const bf16x8*)(vg + (size_t)srow0 * 2048 + sc16 * 8);
            const bf16x8 v1 = *(const bf16x8*)(vg + (size_t)srow1 * 2048 + sc16 * 8);
            *(bf16x8*)((char*)(Ks + srow0 * 64) + ((sc16 * 16) ^ ((srow0 & 7) << 4))) = k0;
            *(bf16x8*)((char*)(Ks + srow1 * 64) + ((sc16 * 16) ^ ((srow1 & 7) << 4))) = k1;
            *(bf16x8*)((char*)(Vs + srow0 * 64) + ((sc16 * 16) ^ ((srow0 & 7) << 4))) = v0;
            *(bf16x8*)((char*)(Vs + srow1 * 64) + ((sc16 * 16) ^ ((srow1 & 7) << 4))) = v1;
        }
        __syncthreads();

        // ---- S = (Q*0.125) @ K^T ----
        f32x4 sacc[4];
        #pragma unroll
        for (int kb = 0; kb < 4; ++kb) {
            const int krow = kb * 16 + ll;
            const char* kr = (const char*)(Ks + krow * 64);
            const int sw = (krow & 7) << 4;
            const bf16x8 b0 = *(const bf16x8*)(kr + ((lg * 16) ^ sw));
            const bf16x8 b1 = *(const bf16x8*)(kr + ((64 + lg * 16) ^ sw));
            sacc[kb] = __builtin_amdgcn_mfma_f32_16x16x32_bf16(aq0, b0, (f32x4)(0.0f), 0, 0, 0);
            sacc[kb] = __builtin_amdgcn_mfma_f32_16x16x32_bf16(aq1, b1, sacc[kb], 0, 0, 0);
        }

        // ---- causal mask + online softmax ----
        float sc_[4][4];
        const bool diag = (kt == qt);
        #pragma unroll
        for (int kb = 0; kb < 4; ++kb) {
            #pragma unroll
            for (int r = 0; r < 4; ++r) {
                float v = sacc[kb][r];
                if (diag && (kb * 16 + ll) > (w * 16 + lg * 4 + r)) v = -3e38f;
                sc_[kb][r] = v;
            }
        }
        float rmax[4];
        #pragma unroll
        for (int r = 0; r < 4; ++r)
            rmax[r] = fmaxf(fmaxf(sc_[0][r], sc_[1][r]), fmaxf(sc_[2][r], sc_[3][r]));
        #pragma unroll
        for (int st = 0; st < 4; ++st) {
            const int off = 1 << st;
            #pragma unroll
            for (int r = 0; r < 4; ++r)
                rmax[r] = fmaxf(rmax[r], __shfl_xor(rmax[r], off));
        }
        float alpha[4], rsum[4];
        #pragma unroll
        for (int r = 0; r < 4; ++r) {
            const float mn = fmaxf(m_i[r], rmax[r]);
            alpha[r] = __expf(m_i[r] - mn);
            m_i[r] = mn;
            rsum[r] = 0.0f;
        }
        #pragma unroll
        for (int kb = 0; kb < 4; ++kb) {
            #pragma unroll
            for (int r = 0; r < 4; ++r) {
                const float p = __expf(sc_[kb][r] - m_i[r]);
                sc_[kb][r] = p;
                rsum[r] += p;
            }
        }
        #pragma unroll
        for (int st = 0; st < 4; ++st) {
            const int off = 1 << st;
            #pragma unroll
            for (int r = 0; r < 4; ++r)
                rsum[r] += __shfl_xor(rsum[r], off);
        }
        #pragma unroll
        for (int r = 0; r < 4; ++r) l_i[r] = l_i[r] * alpha[r] + rsum[r];

        // ---- P -> LDS (bf16, swizzled) ----
        #pragma unroll
        for (int r = 0; r < 4; ++r) {
            const int prow = w * 16 + lg * 4 + r;
            char* pb = (char*)(Ps + prow * 64);
            const int sw = (prow & 7) << 4;
            #pragma unroll
            for (int kb = 0; kb < 4; ++kb)
                *(bf16_t*)(pb + (((kb * 16 + ll) * 2) ^ sw)) = (bf16_t)sc_[kb][r];
        }

        // ---- rescale O, then O += P @ V ----
        #pragma unroll
        for (int db = 0; db < 4; ++db)
            #pragma unroll
            for (int r = 0; r < 4; ++r) o[db][r] *= alpha[r];

        #pragma unroll
        for (int ks = 0; ks < 2; ++ks) {
            const int arow = w * 16 + ll;
            const bf16x8 ap = *(const bf16x8*)((const char*)(Ps + arow * 64) +
                                ((ks * 64 + lg * 16) ^ ((arow & 7) << 4)));
            #pragma unroll
            for (int db = 0; db < 4; ++db) {
                const int vrow = db * 16 + ll;
                const bf16x8 bv = *(const bf16x8*)((const char*)(Vs + vrow * 64) +
                                    ((ks * 64 + lg * 16) ^ ((vrow & 7) << 4)));
                o[db] = __builtin_amdgcn_mfma_f32_16x16x32_bf16(ap, bv, o[db], 0, 0, 0);
            }
        }
    }

    #pragma unroll
    for (int r = 0; r < 4; ++r) {
        const float inv = 1.0f / l_i[r];
        bf16_t* yo = y + (size_t)(q0 + w * 16 + lg * 4 + r) * 768 + h * 64 + ll;
        #pragma unroll
        for (int db = 0; db < 4; ++db)
            yo[db * 16] = (bf16_t)(o[db][r] * inv);
    }
}

// ---------------------------------------------------------------------------
// MFMA NT GEMM: C[M,N] = A[M,K](bf16) * B[N,K](bf16)^T, fp32 accumulate.
// Tile BM x 128, BK=32, 256 threads (4 waves). Double-buffered LDS with
// counted vmcnt (loads stay in flight across raw s_barrier). K % 64 == 0.
// FLAGS: 1=bias, 2=residual into C32, 4=GELU, 8=bf16 out, 16=unembed mode
// ---------------------------------------------------------------------------
template <int FLAGS, int BM>
__global__ __launch_bounds__(256) void gemm_bt(const bf16_t* __restrict__ A,
                                               const bf16_t* __restrict__ B,
                                               const float* __restrict__ bias,
                                               float* __restrict__ C32,
                                               bf16_t* __restrict__ Cb,
                                               int M, int N, int K) {
    constexpr bool HAS_BIAS = (FLAGS & 1) != 0;
    constexpr bool HAS_RES  = (FLAGS & 2) != 0;
    constexpr bool HAS_GELU = (FLAGS & 4) != 0;
    constexpr bool OUT_BF16 = (FLAGS & 8) != 0;
    constexpr bool UNEMB    = (FLAGS & 16) != 0;
    constexpr int  WM       = (BM == 128) ? 64 : 32;
    constexpr int  MI       = WM / 16;
    constexpr int  NLOADS   = (BM == 128) ? 4 : 3;

    __shared__ bf16_t smem[2 * (BM + 128) * 32];
    bf16_t* As0 = smem;
    bf16_t* Bs0 = As0 + BM * 32;
    bf16_t* As1 = Bs0 + 128 * 32;
    bf16_t* Bs1 = As1 + BM * 32;

    const int tid = threadIdx.x;
    const int w = tid >> 6, lane = tid & 63;
    const int bm = (UNEMB ? blockIdx.x : blockIdx.y) * BM;
    const int bn = (UNEMB ? blockIdx.y : blockIdx.x) * 128;
    const int wm = (w >> 1) * WM, wn = (w & 1) * 64;

    const int sc = (lane & 3) * 8;
    const int srB = w * 32 + (lane >> 2);
    const bf16_t* gB0 = B + (size_t)(bn + srB) * K + sc;
    const bf16_t* gB1 = gB0 + (size_t)16 * K;
    const int srA = (BM == 128) ? srB : (w * 16 + (lane >> 2));
    const bf16_t* gA0 = A + (size_t)(bm + srA) * K + sc;
    const bf16_t* gA1 = gA0 + (size_t)16 * K;
    const int ldsA = ((BM == 128) ? (w * 32) : (w * 16)) * 32;  // wave-uniform
    const int ldsB = (w * 32) * 32;

    const int mrow  = lane & 15;
    const int khalf = (lane >> 4) * 8;

    f32x4 acc[MI][4];
    #pragma unroll
    for (int i = 0; i < MI; ++i)
        #pragma unroll
        for (int j = 0; j < 4; ++j) acc[i][j] = (f32x4)(0.0f);

    auto stage = [&](bf16_t* Ap, bf16_t* Bp, int kk) {
        gl_lds16(gA0 + kk, Ap + ldsA);
        if constexpr (BM == 128) gl_lds16(gA1 + kk, Ap + ldsA + 16 * 32);
        gl_lds16(gB0 + kk, Bp + ldsB);
        gl_lds16(gB1 + kk, Bp + ldsB + 16 * 32);
    };
    auto compute = [&](const bf16_t* Ap, const bf16_t* Bp) {
        bf16x8 af[MI], bfr[4];
        #pragma unroll
        for (int i = 0; i < MI; ++i)
            af[i] = *(const bf16x8*)(Ap + (wm + i * 16 + mrow) * 32 + khalf);
        #pragma unroll
        for (int j = 0; j < 4; ++j)
            bfr[j] = *(const bf16x8*)(Bp + (wn + j * 16 + mrow) * 32 + khalf);
        #pragma unroll
        for (int i = 0; i < MI; ++i)
            #pragma unroll
            for (int j = 0; j < 4; ++j)
                acc[i][j] = __builtin_amdgcn_mfma_f32_16x16x32_bf16(
                    af[i], bfr[j], acc[i][j], 0, 0, 0);
    };

    stage(As0, Bs0, 0);
    for (int k0 = 0; k0 < K; k0 += 64) {
        // phase A: compute buf0 @ k0, prefetch buf1 @ k0+32 (always valid)
        stage(As1, Bs1, k0 + 32);
        wait_vm<NLOADS>();
        __builtin_amdgcn_s_barrier();
        __builtin_amdgcn_sched_barrier(0);
        compute(As0, Bs0);
        __builtin_amdgcn_sched_barrier(0);
        __builtin_amdgcn_s_barrier();
        // phase B: compute buf1 @ k0+32, prefetch buf0 @ k0+64
        const bool more = (k0 + 64) < K;
        if (more) stage(As0, Bs0, k0 + 64);
        if (more) wait_vm<NLOADS>(); else wait_vm<0>();
        __builtin_amdgcn_s_barrier();
        __builtin_amdgcn_sched_barrier(0);
        compute(As1, Bs1);
        __builtin_amdgcn_sched_barrier(0);
        __builtin_amdgcn_s_barrier();
    }

    const int ccol = lane & 15;
    const int crow = (lane >> 4) * 4;

    if constexpr (UNEMB) {
        // transpose epilogue: acc -> LDS -> coalesced float4 NT stores
        __syncthreads();
        float* ep = (float*)smem + (size_t)w * (16 * 68);
        const int rl = lane >> 2, c4 = (lane & 3) * 16;
        #pragma unroll
        for (int i = 0; i < MI; ++i) {
            #pragma unroll
            for (int j = 0; j < 4; ++j) {
                #pragma unroll
                for (int r = 0; r < 4; ++r) {
                    float v = acc[i][j][r];
                    if constexpr (HAS_BIAS) v += bias[bn + wn + j * 16 + ccol];
                    ep[(crow + r) * 68 + j * 16 + ccol] = v;
                }
            }
            asm volatile("s_waitcnt lgkmcnt(0)" ::: "memory");
            __builtin_amdgcn_sched_barrier(0);
            float* dst = C32 + (size_t)(bm + wm + i * 16 + rl) * N + bn + wn + c4;
            #pragma unroll
            for (int c = 0; c < 4; ++c) {
                const f32x4 v4 = *(const f32x4*)(ep + rl * 68 + c4 + c * 4);
                __builtin_nontemporal_store(v4, (f32x4*)(dst + c * 4));
            }
            asm volatile("s_waitcnt lgkmcnt(0)" ::: "memory");
            __builtin_amdgcn_sched_barrier(0);
        }
        return;
    }

    #pragma unroll
    for (int i = 0; i < MI; ++i) {
        #pragma unroll
        for (int j = 0; j < 4; ++j) {
            const int col = bn + wn + j * 16 + ccol;
            #pragma unroll
            for (int r = 0; r < 4; ++r) {
                const int row = bm + wm + i * 16 + crow + r;
                float v = acc[i][j][r];
                if constexpr (HAS_BIAS) v += bias[col];
                if constexpr (HAS_GELU) v = 0.5f * v * (1.0f + erff(v * 0.70710678f));
                const size_t off = (size_t)row * N + col;
                if constexpr (HAS_RES) v += C32[off];
                if constexpr (OUT_BF16) Cb[off] = (bf16_t)v;
                else C32[off] = v;
            }
        }
    }
}

// ---------------------------------------------------------------------------
// Host launch
// ---------------------------------------------------------------------------
extern "C" void kernel_launch(void* const* d_in, const int* in_sizes, int n_in,
                              void* d_out, int out_size, void* d_ws, size_t ws_size,
                              hipStream_t stream) {
    const int T = 2048, D = 768, NH = 12, L = 4, V = 32000;
    const int D3 = 3 * D, D4 = 4 * D;

    const int*   idx        = (const int*)d_in[0];
    const float* wte        = (const float*)d_in[1];
    const float* ln1_w      = (const float*)d_in[2];
    const float* attn_w     = (const float*)d_in[3];
    const float* attnproj_w = (const float*)d_in[4];
    const float* ln2_w      = (const float*)d_in[5];
    const float* fc_w       = (const float*)d_in[6];
    const float* fc_b       = (const float*)d_in[7];
    const float* proj_w     = (const float*)d_in[8];
    const float* proj_b     = (const float*)d_in[9];
    const float* lnf_w      = (const float*)d_in[10];
    const float* unemb_b    = (const float*)d_in[11];
    float* out = (float*)d_out;

    // workspace layout (~92.1 MB)
    char* p = (char*)d_ws;
    float*  X      = (float*)p;   p += (size_t)T * D * 4;
    bf16_t* Hb     = (bf16_t*)p;  p += (size_t)T * D * 2;
    float*  QKV    = (float*)p;
    bf16_t* Mb     = (bf16_t*)p;  p += (size_t)T * D3 * 4;
    bf16_t* wte_b  = (bf16_t*)p;  p += (size_t)V * D * 2;
    bf16_t* w_attn = (bf16_t*)p;  p += (size_t)D3 * D * 2;
    bf16_t* w_apr  = (bf16_t*)p;  p += (size_t)D * D * 2;
    bf16_t* w_fc   = (bf16_t*)p;  p += (size_t)D4 * D * 2;
    bf16_t* w_proj = (bf16_t*)p;  p += (size_t)D * D4 * 2;
    float*  rtab   = (float*)p;   p += (size_t)T * 32 * 2 * 4;   // cos/sin table

    // Q/K/V^T bf16 buffers overlay wte_b (dead until after the layer loop)
    bf16_t* Qb  = wte_b;
    bf16_t* Kbf = Qb  + (size_t)NH * T * 64;
    bf16_t* Vtg = Kbf + (size_t)NH * T * 64;

    embed_kernel<<<T, 256, 0, stream>>>(idx, wte, X);
    rope_table<<<T * 32 / 256, 256, 0, stream>>>(rtab);

    const int na = D3 * D / 4, nb = D * D / 4, nc = D4 * D / 4, nd = D * D4 / 4;
    const int ntot = na + nb + nc + nd;

    for (int l = 0; l < L; ++l) {
        // all 4 weight casts in one launch
        cvt4_kernel<<<(ntot + 255) / 256, 256, 0, stream>>>(
            attn_w + (size_t)l * D3 * D, attnproj_w + (size_t)l * D * D,
            fc_w + (size_t)l * D4 * D, proj_w + (size_t)l * D * D4,
            w_attn, w_apr, w_fc, w_proj, na, nb, nc, nd);

        // h = LN1(x)  (bf16)
        ln_kernel<<<T, 256, 0, stream>>>(X, ln1_w + (size_t)l * D, Hb);
        // qkv = h @ attn_w^T  (fp32 out)
        gemm_bt<0, 128><<<dim3(D3 / 128, T / 128), 256, 0, stream>>>(
            Hb, w_attn, nullptr, QKV, nullptr, T, D3, D);
        // RoPE + bf16 pack + V transpose
        rope_prep<<<dim3(T / 64, NH), 256, 0, stream>>>(QKV, rtab, Qb, Kbf, Vtg);
        // y = attn(q,k,v)  (bf16 into Hb)
        attn_mfma<<<dim3(T / 64, NH), 256, 0, stream>>>(Qb, Kbf, Vtg, Hb);
        // x += y @ attnproj_w^T   (BM=64: 192 blocks)
        gemm_bt<2, 64><<<dim3(D / 128, T / 64), 256, 0, stream>>>(
            Hb, w_apr, nullptr, X, nullptr, T, D, D);
        // h = LN2(x)
        ln_kernel<<<T, 256, 0, stream>>>(X, ln2_w + (size_t)l * D, Hb);
        // m = gelu(h @ fc_w^T + fc_b)  (bf16 out)
        gemm_bt<13, 128><<<dim3(D4 / 128, T / 128), 256, 0, stream>>>(
            Hb, w_fc, fc_b + (size_t)l * D4, nullptr, Mb, T, D4, D);
        // x += m @ proj_w^T + proj_b   (BM=64)
        gemm_bt<3, 64><<<dim3(D / 128, T / 64), 256, 0, stream>>>(
            Mb, w_proj, proj_b + (size_t)l * D, X, nullptr, T, D, D4);
    }

    // hf = LN(x); logits = hf @ wte^T + unemb_b  (fp32 out)
    ln_kernel<<<T, 256, 0, stream>>>(X, lnf_w, Hb);
    {
        const int n4 = V * D / 4;   // deferred: wte_b region was reused above
        cvt_kernel<<<(n4 + 255) / 256, 256, 0, stream>>>(wte, wte_b, n4);
    }
    // unembed mode: grid x = M tiles (fast axis shares B panel), NT f32x4 C
    gemm_bt<17, 128><<<dim3(T / 128, V / 128), 256, 0, stream>>>(
        Hb, wte_b, unemb_b, out, nullptr, T, V, D);
}

// Round 5
// 1288.622 us; speedup vs baseline: 1.2282x; 1.2282x over previous
//
#include <hip/hip_runtime.h>
#include <hip/hip_bf16.h>

typedef __bf16 bf16_t;
typedef __bf16 bf16x8 __attribute__((ext_vector_type(8)));
typedef __bf16 bf16x4 __attribute__((ext_vector_type(4)));
typedef float  f32x4  __attribute__((ext_vector_type(4)));

// async global->LDS, 16B per lane. LDS dest = wave-uniform base + lane*16.
__device__ __forceinline__ void gl_lds16(const void* g, void* l) {
    __builtin_amdgcn_global_load_lds(
        (__attribute__((address_space(1))) void*)g,
        (__attribute__((address_space(3))) void*)l, 16, 0, 0);
}

template <int N>
__device__ __forceinline__ void wait_vm() {
    if constexpr (N == 0)      asm volatile("s_waitcnt vmcnt(0)" ::: "memory");
    else if constexpr (N == 3) asm volatile("s_waitcnt vmcnt(3)" ::: "memory");
    else                       asm volatile("s_waitcnt vmcnt(4)" ::: "memory");
}

// ---------------------------------------------------------------------------
// fp32 -> bf16 cast, vectorized (n must be multiple of 4)
// ---------------------------------------------------------------------------
__global__ void cvt_kernel(const float* __restrict__ in, bf16_t* __restrict__ out,
                           int n4) {
    const int i = blockIdx.x * 256 + threadIdx.x;
    if (i < n4) {
        const float4 v = ((const float4*)in)[i];
        bf16x4 o;
        o.x = (bf16_t)v.x; o.y = (bf16_t)v.y; o.z = (bf16_t)v.z; o.w = (bf16_t)v.w;
        ((bf16x4*)out)[i] = o;
    }
}

// 4 segments in one launch (per-layer weight casts)
__global__ void cvt4_kernel(const float* __restrict__ s0, const float* __restrict__ s1,
                            const float* __restrict__ s2, const float* __restrict__ s3,
                            bf16_t* __restrict__ d0, bf16_t* __restrict__ d1,
                            bf16_t* __restrict__ d2, bf16_t* __restrict__ d3,
                            int n0, int n1, int n2, int n3) {
    int j = blockIdx.x * 256 + threadIdx.x;
    const float* s; bf16_t* d;
    if (j < n0) { s = s0; d = d0; }
    else {
        j -= n0;
        if (j < n1) { s = s1; d = d1; }
        else {
            j -= n1;
            if (j < n2) { s = s2; d = d2; }
            else {
                j -= n2;
                if (j >= n3) return;
                s = s3; d = d3;
            }
        }
    }
    const float4 v = ((const float4*)s)[j];
    bf16x4 o;
    o.x = (bf16_t)v.x; o.y = (bf16_t)v.y; o.z = (bf16_t)v.z; o.w = (bf16_t)v.w;
    ((bf16x4*)d)[j] = o;
}

// ---------------------------------------------------------------------------
// RoPE cos/sin table: tab[t*32+i] = {cos, sin}(t * 10000^(-i/32))
// ---------------------------------------------------------------------------
__global__ void rope_table(float* __restrict__ tab) {
    const int i = blockIdx.x * 256 + threadIdx.x;   // T*32 items
    const int t = i >> 5, f = i & 31;
    const float inv_freq = __powf(10000.0f, -(float)f * (1.0f / 32.0f));
    const float ang = (float)t * inv_freq;
    float s, c;
    __sincosf(ang, &s, &c);
    tab[2 * i]     = c;
    tab[2 * i + 1] = s;
}

// ---------------------------------------------------------------------------
// Embedding gather: x[t,:] = wte[idx[t],:]  (fp32, float4)
// ---------------------------------------------------------------------------
__global__ void embed_kernel(const int* __restrict__ idx,
                             const float* __restrict__ wte,
                             float* __restrict__ x) {
    const int t = blockIdx.x;
    const int row = idx[t];
    const float4* w = (const float4*)(wte + (size_t)row * 768);
    float4* o = (float4*)(x + (size_t)t * 768);
    if (threadIdx.x < 192) o[threadIdx.x] = w[threadIdx.x];
}

// ---------------------------------------------------------------------------
// LayerNorm: out(bf16) = (x - mu) * rsqrt(var + eps) * w      D = 768
// ---------------------------------------------------------------------------
__global__ __launch_bounds__(256) void ln_kernel(const float* __restrict__ x,
                                                 const float* __restrict__ w,
                                                 bf16_t* __restrict__ out) {
    const int t = blockIdx.x, tid = threadIdx.x;
    __shared__ float red[256];
    const float* xr = x + (size_t)t * 768;
    const float v0 = xr[tid], v1 = xr[tid + 256], v2 = xr[tid + 512];
    red[tid] = v0 + v1 + v2;
    __syncthreads();
    for (int s = 128; s > 0; s >>= 1) {
        if (tid < s) red[tid] += red[tid + s];
        __syncthreads();
    }
    const float mu = red[0] * (1.0f / 768.0f);
    __syncthreads();
    const float d0 = v0 - mu, d1 = v1 - mu, d2 = v2 - mu;
    red[tid] = d0 * d0 + d1 * d1 + d2 * d2;
    __syncthreads();
    for (int s = 128; s > 0; s >>= 1) {
        if (tid < s) red[tid] += red[tid + s];
        __syncthreads();
    }
    const float rstd = rsqrtf(red[0] * (1.0f / 768.0f) + 1e-5f);
    bf16_t* orow = out + (size_t)t * 768;
    orow[tid]       = (bf16_t)(d0 * rstd * w[tid]);
    orow[tid + 256] = (bf16_t)(d1 * rstd * w[tid + 256]);
    orow[tid + 512] = (bf16_t)(d2 * rstd * w[tid + 512]);
}

// ---------------------------------------------------------------------------
// RoPE + bf16 pack + V transpose. grid (T/64, NH), block 256.
// ---------------------------------------------------------------------------
__global__ __launch_bounds__(256) void rope_prep(const float* __restrict__ qkv,
                                                 const float* __restrict__ tab,
                                                 bf16_t* __restrict__ Qb,
                                                 bf16_t* __restrict__ Kb,
                                                 bf16_t* __restrict__ Vt) {
    const int t0 = blockIdx.x * 64, h = blockIdx.y;
    const int tid = threadIdx.x;
    __shared__ bf16_t vt[64][65];   // [d][k], padded row

    #pragma unroll
    for (int it = 0; it < 16; ++it) {
        const int item = it * 256 + tid;
        const int tl = item >> 6;
        const int which = (item >> 5) & 1;   // 0 = Q, 1 = K
        const int i = item & 31;
        const float* src = qkv + (size_t)(t0 + tl) * 2304 + which * 768 + h * 64;
        const float2 cs = ((const float2*)tab)[(t0 + tl) * 32 + i];
        const float c = cs.x, s = cs.y;
        const float x1 = src[i], x2 = src[i + 32];
        bf16_t* dst = (which ? Kb : Qb) + ((size_t)h * 2048 + t0 + tl) * 64;
        const float sc = which ? 1.0f : 0.125f;   // fold attn scale into Q
        dst[i]      = (bf16_t)((x1 * c - x2 * s) * sc);
        dst[i + 32] = (bf16_t)((x1 * s + x2 * c) * sc);
    }

    #pragma unroll
    for (int pass = 0; pass < 4; ++pass) {
        const int r = pass * 16 + (tid >> 4);   // key row 0..63
        const int c = (tid & 15) * 4;           // d 0..60
        const float4 v = *(const float4*)(qkv + (size_t)(t0 + r) * 2304 + 1536 + h * 64 + c);
        vt[c + 0][r] = (bf16_t)v.x;
        vt[c + 1][r] = (bf16_t)v.y;
        vt[c + 2][r] = (bf16_t)v.z;
        vt[c + 3][r] = (bf16_t)v.w;
    }
    __syncthreads();
    #pragma unroll
    for (int pass = 0; pass < 2; ++pass) {
        const int d = pass * 32 + (tid >> 3);
        const int k8 = (tid & 7) * 8;
        bf16x8 vv;
        #pragma unroll
        for (int j = 0; j < 8; ++j) vv[j] = vt[d][k8 + j];
        *(bf16x8*)(Vt + ((size_t)h * 64 + d) * 2048 + t0 + k8) = vv;
    }
}

// ---------------------------------------------------------------------------
// MFMA flash attention. Block = (64-query tile, head), 256 threads (4 waves).
// ---------------------------------------------------------------------------
__global__ __launch_bounds__(256) void attn_mfma(const bf16_t* __restrict__ Qb,
                                                 const bf16_t* __restrict__ Kb,
                                                 const bf16_t* __restrict__ Vt,
                                                 bf16_t* __restrict__ y) {
    const int qt = (int)gridDim.x - 1 - (int)blockIdx.x;  // longest blocks first
    const int h  = blockIdx.y;
    const int q0 = qt * 64;
    const int tid = threadIdx.x;
    const int w = tid >> 6, lane = tid & 63;
    const int lg = lane >> 4;       // lane group 0..3
    const int ll = lane & 15;

    __shared__ bf16_t Ks[64 * 64];  // [key][d], swizzled
    __shared__ bf16_t Vs[64 * 64];  // [d][key] (V^T tile), swizzled
    __shared__ bf16_t Ps[64 * 64];  // [q][key], swizzled (per-wave private rows)

    bf16x8 aq0, aq1;
    {
        const bf16_t* qp = Qb + ((size_t)h * 2048 + q0 + w * 16 + ll) * 64 + lg * 8;
        aq0 = *(const bf16x8*)qp;
        aq1 = *(const bf16x8*)(qp + 32);
    }

    f32x4 o[4];
    #pragma unroll
    for (int i = 0; i < 4; ++i) o[i] = (f32x4)(0.0f);
    float m_i[4], l_i[4];
    #pragma unroll
    for (int r = 0; r < 4; ++r) { m_i[r] = -3e38f; l_i[r] = 0.0f; }

    const int srow0 = tid >> 3;          // rows 0..31
    const int srow1 = srow0 + 32;        // rows 32..63
    const int sc16  = tid & 7;           // 16B chunk within 128B row

    const bf16_t* Kbase = Kb + (size_t)h * 2048 * 64;
    const bf16_t* Vbase = Vt + (size_t)h * 64 * 2048;

    for (int kt = 0; kt <= qt; ++kt) {
        __syncthreads();
        {
            const bf16_t* kg = Kbase + (size_t)(kt * 64) * 64;
            const bf16x8 k0 = *(const bf16x8*)(kg + srow0 * 64 + sc16 * 8);
            const bf16x8 k1 = *(const bf16x8*)(kg + srow1 * 64 + sc16 * 8);
            const bf16_t* vg = Vbase + kt * 64;
            const bf16x8 v0 = *(const bf16x8*)(vg + (size_t)srow0 * 2048 + sc16 * 8);
            const bf16x8 v1 = *(const bf16x8*)(vg + (size_t)srow1 * 2048 + sc16 * 8);
            *(bf16x8*)((char*)(Ks + srow0 * 64) + ((sc16 * 16) ^ ((srow0 & 7) << 4))) = k0;
            *(bf16x8*)((char*)(Ks + srow1 * 64) + ((sc16 * 16) ^ ((srow1 & 7) << 4))) = k1;
            *(bf16x8*)((char*)(Vs + srow0 * 64) + ((sc16 * 16) ^ ((srow0 & 7) << 4))) = v0;
            *(bf16x8*)((char*)(Vs + srow1 * 64) + ((sc16 * 16) ^ ((srow1 & 7) << 4))) = v1;
        }
        __syncthreads();

        // ---- S = (Q*0.125) @ K^T ----
        f32x4 sacc[4];
        #pragma unroll
        for (int kb = 0; kb < 4; ++kb) {
            const int krow = kb * 16 + ll;
            const char* kr = (const char*)(Ks + krow * 64);
            const int sw = (krow & 7) << 4;
            const bf16x8 b0 = *(const bf16x8*)(kr + ((lg * 16) ^ sw));
            const bf16x8 b1 = *(const bf16x8*)(kr + ((64 + lg * 16) ^ sw));
            sacc[kb] = __builtin_amdgcn_mfma_f32_16x16x32_bf16(aq0, b0, (f32x4)(0.0f), 0, 0, 0);
            sacc[kb] = __builtin_amdgcn_mfma_f32_16x16x32_bf16(aq1, b1, sacc[kb], 0, 0, 0);
        }

        // ---- causal mask + online softmax ----
        float sc_[4][4];
        const bool diag = (kt == qt);
        #pragma unroll
        for (int kb = 0; kb < 4; ++kb) {
            #pragma unroll
            for (int r = 0; r < 4; ++r) {
                float v = sacc[kb][r];
                if (diag && (kb * 16 + ll) > (w * 16 + lg * 4 + r)) v = -3e38f;
                sc_[kb][r] = v;
            }
        }
        float rmax[4];
        #pragma unroll
        for (int r = 0; r < 4; ++r)
            rmax[r] = fmaxf(fmaxf(sc_[0][r], sc_[1][r]), fmaxf(sc_[2][r], sc_[3][r]));
        #pragma unroll
        for (int st = 0; st < 4; ++st) {
            const int off = 1 << st;
            #pragma unroll
            for (int r = 0; r < 4; ++r)
                rmax[r] = fmaxf(rmax[r], __shfl_xor(rmax[r], off));
        }
        float alpha[4], rsum[4];
        #pragma unroll
        for (int r = 0; r < 4; ++r) {
            const float mn = fmaxf(m_i[r], rmax[r]);
            alpha[r] = __expf(m_i[r] - mn);
            m_i[r] = mn;
            rsum[r] = 0.0f;
        }
        #pragma unroll
        for (int kb = 0; kb < 4; ++kb) {
            #pragma unroll
            for (int r = 0; r < 4; ++r) {
                const float p = __expf(sc_[kb][r] - m_i[r]);
                sc_[kb][r] = p;
                rsum[r] += p;
            }
        }
        #pragma unroll
        for (int st = 0; st < 4; ++st) {
            const int off = 1 << st;
            #pragma unroll
            for (int r = 0; r < 4; ++r)
                rsum[r] += __shfl_xor(rsum[r], off);
        }
        #pragma unroll
        for (int r = 0; r < 4; ++r) l_i[r] = l_i[r] * alpha[r] + rsum[r];

        // ---- P -> LDS (bf16, swizzled) ----
        #pragma unroll
        for (int r = 0; r < 4; ++r) {
            const int prow = w * 16 + lg * 4 + r;
            char* pb = (char*)(Ps + prow * 64);
            const int sw = (prow & 7) << 4;
            #pragma unroll
            for (int kb = 0; kb < 4; ++kb)
                *(bf16_t*)(pb + (((kb * 16 + ll) * 2) ^ sw)) = (bf16_t)sc_[kb][r];
        }

        // ---- rescale O, then O += P @ V ----
        #pragma unroll
        for (int db = 0; db < 4; ++db)
            #pragma unroll
            for (int r = 0; r < 4; ++r) o[db][r] *= alpha[r];

        #pragma unroll
        for (int ks = 0; ks < 2; ++ks) {
            const int arow = w * 16 + ll;
            const bf16x8 ap = *(const bf16x8*)((const char*)(Ps + arow * 64) +
                                ((ks * 64 + lg * 16) ^ ((arow & 7) << 4)));
            #pragma unroll
            for (int db = 0; db < 4; ++db) {
                const int vrow = db * 16 + ll;
                const bf16x8 bv = *(const bf16x8*)((const char*)(Vs + vrow * 64) +
                                    ((ks * 64 + lg * 16) ^ ((vrow & 7) << 4)));
                o[db] = __builtin_amdgcn_mfma_f32_16x16x32_bf16(ap, bv, o[db], 0, 0, 0);
            }
        }
    }

    #pragma unroll
    for (int r = 0; r < 4; ++r) {
        const float inv = 1.0f / l_i[r];
        bf16_t* yo = y + (size_t)(q0 + w * 16 + lg * 4 + r) * 768 + h * 64 + ll;
        #pragma unroll
        for (int db = 0; db < 4; ++db)
            yo[db * 16] = (bf16_t)(o[db][r] * inv);
    }
}

// ---------------------------------------------------------------------------
// MFMA NT GEMM: C[M,N] = A[M,K](bf16) * B[N,K](bf16)^T, fp32 accumulate.
// Tile BM x 128, BK=32, 256 threads (4 waves). Double-buffered LDS with
// counted vmcnt (loads stay in flight across raw s_barrier). K % 64 == 0.
// FLAGS: 1=bias, 2=residual into C32, 4=GELU, 8=bf16 out,
//        16=unembed mode (XCD-partitioned panel remap: each XCD owns a
//        contiguous range of N-panels so B panels are fetched by ONE L2)
// ---------------------------------------------------------------------------
template <int FLAGS, int BM>
__global__ __launch_bounds__(256) void gemm_bt(const bf16_t* __restrict__ A,
                                               const bf16_t* __restrict__ B,
                                               const float* __restrict__ bias,
                                               float* __restrict__ C32,
                                               bf16_t* __restrict__ Cb,
                                               int M, int N, int K) {
    constexpr bool HAS_BIAS = (FLAGS & 1) != 0;
    constexpr bool HAS_RES  = (FLAGS & 2) != 0;
    constexpr bool HAS_GELU = (FLAGS & 4) != 0;
    constexpr bool OUT_BF16 = (FLAGS & 8) != 0;
    constexpr bool UNEMB    = (FLAGS & 16) != 0;
    constexpr int  WM       = (BM == 128) ? 64 : 32;
    constexpr int  MI       = WM / 16;
    constexpr int  NLOADS   = (BM == 128) ? 4 : 3;

    __shared__ bf16_t smem[2 * (BM + 128) * 32];
    bf16_t* As0 = smem;
    bf16_t* Bs0 = As0 + BM * 32;
    bf16_t* As1 = Bs0 + 128 * 32;
    bf16_t* Bs1 = As1 + BM * 32;

    const int tid = threadIdx.x;
    const int w = tid >> 6, lane = tid & 63;

    int bm, bn;
    if constexpr (UNEMB) {
        // grid = (M/BM = 16, N/128). Remap so each XCD owns a contiguous
        // panel range: xcd = bid%8 (HW round-robin), slot = bid/8.
        const int bid  = (int)blockIdx.y * (int)gridDim.x + (int)blockIdx.x;
        const int per  = ((int)gridDim.x * (int)gridDim.y) >> 3;   // blocks/XCD
        const int nid  = (bid & 7) * per + (bid >> 3);
        bm = (nid & 15) * BM;          // M-tile fast: 16 blocks share a panel
        bn = (nid >> 4) * 128;
    } else {
        bm = blockIdx.y * BM;
        bn = blockIdx.x * 128;
    }
    const int wm = (w >> 1) * WM, wn = (w & 1) * 64;

    const int sc = (lane & 3) * 8;
    const int srB = w * 32 + (lane >> 2);
    const bf16_t* gB0 = B + (size_t)(bn + srB) * K + sc;
    const bf16_t* gB1 = gB0 + (size_t)16 * K;
    const int srA = (BM == 128) ? srB : (w * 16 + (lane >> 2));
    const bf16_t* gA0 = A + (size_t)(bm + srA) * K + sc;
    const bf16_t* gA1 = gA0 + (size_t)16 * K;
    const int ldsA = ((BM == 128) ? (w * 32) : (w * 16)) * 32;  // wave-uniform
    const int ldsB = (w * 32) * 32;

    const int mrow  = lane & 15;
    const int khalf = (lane >> 4) * 8;

    f32x4 acc[MI][4];
    #pragma unroll
    for (int i = 0; i < MI; ++i)
        #pragma unroll
        for (int j = 0; j < 4; ++j) acc[i][j] = (f32x4)(0.0f);

    auto stage = [&](bf16_t* Ap, bf16_t* Bp, int kk) {
        gl_lds16(gA0 + kk, Ap + ldsA);
        if constexpr (BM == 128) gl_lds16(gA1 + kk, Ap + ldsA + 16 * 32);
        gl_lds16(gB0 + kk, Bp + ldsB);
        gl_lds16(gB1 + kk, Bp + ldsB + 16 * 32);
    };
    auto compute = [&](const bf16_t* Ap, const bf16_t* Bp) {
        bf16x8 af[MI], bfr[4];
        #pragma unroll
        for (int i = 0; i < MI; ++i)
            af[i] = *(const bf16x8*)(Ap + (wm + i * 16 + mrow) * 32 + khalf);
        #pragma unroll
        for (int j = 0; j < 4; ++j)
            bfr[j] = *(const bf16x8*)(Bp + (wn + j * 16 + mrow) * 32 + khalf);
        #pragma unroll
        for (int i = 0; i < MI; ++i)
            #pragma unroll
            for (int j = 0; j < 4; ++j)
                acc[i][j] = __builtin_amdgcn_mfma_f32_16x16x32_bf16(
                    af[i], bfr[j], acc[i][j], 0, 0, 0);
    };

    stage(As0, Bs0, 0);
    for (int k0 = 0; k0 < K; k0 += 64) {
        // phase A: compute buf0 @ k0, prefetch buf1 @ k0+32 (always valid)
        stage(As1, Bs1, k0 + 32);
        wait_vm<NLOADS>();
        __builtin_amdgcn_s_barrier();
        __builtin_amdgcn_sched_barrier(0);
        compute(As0, Bs0);
        __builtin_amdgcn_sched_barrier(0);
        __builtin_amdgcn_s_barrier();
        // phase B: compute buf1 @ k0+32, prefetch buf0 @ k0+64
        const bool more = (k0 + 64) < K;
        if (more) stage(As0, Bs0, k0 + 64);
        if (more) wait_vm<NLOADS>(); else wait_vm<0>();
        __builtin_amdgcn_s_barrier();
        __builtin_amdgcn_sched_barrier(0);
        compute(As1, Bs1);
        __builtin_amdgcn_sched_barrier(0);
        __builtin_amdgcn_s_barrier();
    }

    const int ccol = lane & 15;
    const int crow = (lane >> 4) * 4;
    #pragma unroll
    for (int i = 0; i < MI; ++i) {
        #pragma unroll
        for (int j = 0; j < 4; ++j) {
            const int col = bn + wn + j * 16 + ccol;
            #pragma unroll
            for (int r = 0; r < 4; ++r) {
                const int row = bm + wm + i * 16 + crow + r;
                float v = acc[i][j][r];
                if constexpr (HAS_BIAS) v += bias[col];
                if constexpr (HAS_GELU) v = 0.5f * v * (1.0f + erff(v * 0.70710678f));
                const size_t off = (size_t)row * N + col;
                if constexpr (HAS_RES) v += C32[off];
                if constexpr (OUT_BF16) Cb[off] = (bf16_t)v;
                else C32[off] = v;
            }
        }
    }
}

// ---------------------------------------------------------------------------
// Host launch
// ---------------------------------------------------------------------------
extern "C" void kernel_launch(void* const* d_in, const int* in_sizes, int n_in,
                              void* d_out, int out_size, void* d_ws, size_t ws_size,
                              hipStream_t stream) {
    const int T = 2048, D = 768, NH = 12, L = 4, V = 32000;
    const int D3 = 3 * D, D4 = 4 * D;

    const int*   idx        = (const int*)d_in[0];
    const float* wte        = (const float*)d_in[1];
    const float* ln1_w      = (const float*)d_in[2];
    const float* attn_w     = (const float*)d_in[3];
    const float* attnproj_w = (const float*)d_in[4];
    const float* ln2_w      = (const float*)d_in[5];
    const float* fc_w       = (const float*)d_in[6];
    const float* fc_b       = (const float*)d_in[7];
    const float* proj_w     = (const float*)d_in[8];
    const float* proj_b     = (const float*)d_in[9];
    const float* lnf_w      = (const float*)d_in[10];
    const float* unemb_b    = (const float*)d_in[11];
    float* out = (float*)d_out;

    // workspace layout (~92.1 MB)
    char* p = (char*)d_ws;
    float*  X      = (float*)p;   p += (size_t)T * D * 4;
    bf16_t* Hb     = (bf16_t*)p;  p += (size_t)T * D * 2;
    float*  QKV    = (float*)p;
    bf16_t* Mb     = (bf16_t*)p;  p += (size_t)T * D3 * 4;
    bf16_t* wte_b  = (bf16_t*)p;  p += (size_t)V * D * 2;
    bf16_t* w_attn = (bf16_t*)p;  p += (size_t)D3 * D * 2;
    bf16_t* w_apr  = (bf16_t*)p;  p += (size_t)D * D * 2;
    bf16_t* w_fc   = (bf16_t*)p;  p += (size_t)D4 * D * 2;
    bf16_t* w_proj = (bf16_t*)p;  p += (size_t)D * D4 * 2;
    float*  rtab   = (float*)p;   p += (size_t)T * 32 * 2 * 4;   // cos/sin table

    // Q/K/V^T bf16 buffers overlay wte_b (dead until after the layer loop)
    bf16_t* Qb  = wte_b;
    bf16_t* Kbf = Qb  + (size_t)NH * T * 64;
    bf16_t* Vtg = Kbf + (size_t)NH * T * 64;

    embed_kernel<<<T, 256, 0, stream>>>(idx, wte, X);
    rope_table<<<T * 32 / 256, 256, 0, stream>>>(rtab);

    const int na = D3 * D / 4, nb = D * D / 4, nc = D4 * D / 4, nd = D * D4 / 4;
    const int ntot = na + nb + nc + nd;

    for (int l = 0; l < L; ++l) {
        // all 4 weight casts in one launch
        cvt4_kernel<<<(ntot + 255) / 256, 256, 0, stream>>>(
            attn_w + (size_t)l * D3 * D, attnproj_w + (size_t)l * D * D,
            fc_w + (size_t)l * D4 * D, proj_w + (size_t)l * D * D4,
            w_attn, w_apr, w_fc, w_proj, na, nb, nc, nd);

        // h = LN1(x)  (bf16)
        ln_kernel<<<T, 256, 0, stream>>>(X, ln1_w + (size_t)l * D, Hb);
        // qkv = h @ attn_w^T  (fp32 out)
        gemm_bt<0, 128><<<dim3(D3 / 128, T / 128), 256, 0, stream>>>(
            Hb, w_attn, nullptr, QKV, nullptr, T, D3, D);
        // RoPE + bf16 pack + V transpose
        rope_prep<<<dim3(T / 64, NH), 256, 0, stream>>>(QKV, rtab, Qb, Kbf, Vtg);
        // y = attn(q,k,v)  (bf16 into Hb)
        attn_mfma<<<dim3(T / 64, NH), 256, 0, stream>>>(Qb, Kbf, Vtg, Hb);
        // x += y @ attnproj_w^T   (BM=64: 192 blocks)
        gemm_bt<2, 64><<<dim3(D / 128, T / 64), 256, 0, stream>>>(
            Hb, w_apr, nullptr, X, nullptr, T, D, D);
        // h = LN2(x)
        ln_kernel<<<T, 256, 0, stream>>>(X, ln2_w + (size_t)l * D, Hb);
        // m = gelu(h @ fc_w^T + fc_b)  (bf16 out)
        gemm_bt<13, 128><<<dim3(D4 / 128, T / 128), 256, 0, stream>>>(
            Hb, w_fc, fc_b + (size_t)l * D4, nullptr, Mb, T, D4, D);
        // x += m @ proj_w^T + proj_b   (BM=64)
        gemm_bt<3, 64><<<dim3(D / 128, T / 64), 256, 0, stream>>>(
            Mb, w_proj, proj_b + (size_t)l * D, X, nullptr, T, D, D4);
    }

    // hf = LN(x); logits = hf @ wte^T + unemb_b  (fp32 out)
    ln_kernel<<<T, 256, 0, stream>>>(X, lnf_w, Hb);
    {
        const int n4 = V * D / 4;   // deferred: wte_b region was reused above
        cvt_kernel<<<(n4 + 255) / 256, 256, 0, stream>>>(wte, wte_b, n4);
    }
    // unembed: XCD-partitioned remap (in-kernel), plain coalescing stores
    gemm_bt<17, 128><<<dim3(T / 128, V / 128), 256, 0, stream>>>(
        Hb, wte_b, unemb_b, out, nullptr, T, V, D);
}

// Round 6
// 1232.319 us; speedup vs baseline: 1.2844x; 1.0457x over previous
//
#include <hip/hip_runtime.h>
#include <hip/hip_bf16.h>

typedef __bf16 bf16_t;
typedef __bf16 bf16x8 __attribute__((ext_vector_type(8)));
typedef __bf16 bf16x4 __attribute__((ext_vector_type(4)));
typedef float  f32x4  __attribute__((ext_vector_type(4)));

// async global->LDS, 16B per lane. LDS dest = wave-uniform base + lane*16.
__device__ __forceinline__ void gl_lds16(const void* g, void* l) {
    __builtin_amdgcn_global_load_lds(
        (__attribute__((address_space(1))) void*)g,
        (__attribute__((address_space(3))) void*)l, 16, 0, 0);
}

template <int N>
__device__ __forceinline__ void wait_vm() {
    if constexpr (N == 0)      asm volatile("s_waitcnt vmcnt(0)" ::: "memory");
    else if constexpr (N == 3) asm volatile("s_waitcnt vmcnt(3)" ::: "memory");
    else                       asm volatile("s_waitcnt vmcnt(4)" ::: "memory");
}

// ---------------------------------------------------------------------------
// fp32 -> bf16 cast, vectorized (n must be multiple of 4)
// ---------------------------------------------------------------------------
__global__ void cvt_kernel(const float* __restrict__ in, bf16_t* __restrict__ out,
                           int n4) {
    const int i = blockIdx.x * 256 + threadIdx.x;
    if (i < n4) {
        const float4 v = ((const float4*)in)[i];
        bf16x4 o;
        o.x = (bf16_t)v.x; o.y = (bf16_t)v.y; o.z = (bf16_t)v.z; o.w = (bf16_t)v.w;
        ((bf16x4*)out)[i] = o;
    }
}

// 4 segments in one launch (all-layer weight casts, hoisted out of the loop)
__global__ void cvt4_kernel(const float* __restrict__ s0, const float* __restrict__ s1,
                            const float* __restrict__ s2, const float* __restrict__ s3,
                            bf16_t* __restrict__ d0, bf16_t* __restrict__ d1,
                            bf16_t* __restrict__ d2, bf16_t* __restrict__ d3,
                            int n0, int n1, int n2, int n3) {
    int j = blockIdx.x * 256 + threadIdx.x;
    const float* s; bf16_t* d;
    if (j < n0) { s = s0; d = d0; }
    else {
        j -= n0;
        if (j < n1) { s = s1; d = d1; }
        else {
            j -= n1;
            if (j < n2) { s = s2; d = d2; }
            else {
                j -= n2;
                if (j >= n3) return;
                s = s3; d = d3;
            }
        }
    }
    const float4 v = ((const float4*)s)[j];
    bf16x4 o;
    o.x = (bf16_t)v.x; o.y = (bf16_t)v.y; o.z = (bf16_t)v.z; o.w = (bf16_t)v.w;
    ((bf16x4*)d)[j] = o;
}

// ---------------------------------------------------------------------------
// RoPE cos/sin table: tab[t*32+i] = {cos, sin}(t * 10000^(-i/32))
// ---------------------------------------------------------------------------
__global__ void rope_table(float* __restrict__ tab) {
    const int i = blockIdx.x * 256 + threadIdx.x;   // T*32 items
    const int t = i >> 5, f = i & 31;
    const float inv_freq = __powf(10000.0f, -(float)f * (1.0f / 32.0f));
    const float ang = (float)t * inv_freq;
    float s, c;
    __sincosf(ang, &s, &c);
    tab[2 * i]     = c;
    tab[2 * i + 1] = s;
}

// ---------------------------------------------------------------------------
// Embedding gather: x[t,:] = wte[idx[t],:]  (fp32, float4)
// ---------------------------------------------------------------------------
__global__ void embed_kernel(const int* __restrict__ idx,
                             const float* __restrict__ wte,
                             float* __restrict__ x) {
    const int t = blockIdx.x;
    const int row = idx[t];
    const float4* w = (const float4*)(wte + (size_t)row * 768);
    float4* o = (float4*)(x + (size_t)t * 768);
    if (threadIdx.x < 192) o[threadIdx.x] = w[threadIdx.x];
}

// ---------------------------------------------------------------------------
// LayerNorm: out(bf16) = (x - mu) * rsqrt(var + eps) * w      D = 768
// ---------------------------------------------------------------------------
__global__ __launch_bounds__(256) void ln_kernel(const float* __restrict__ x,
                                                 const float* __restrict__ w,
                                                 bf16_t* __restrict__ out) {
    const int t = blockIdx.x, tid = threadIdx.x;
    __shared__ float red[256];
    const float* xr = x + (size_t)t * 768;
    const float v0 = xr[tid], v1 = xr[tid + 256], v2 = xr[tid + 512];
    red[tid] = v0 + v1 + v2;
    __syncthreads();
    for (int s = 128; s > 0; s >>= 1) {
        if (tid < s) red[tid] += red[tid + s];
        __syncthreads();
    }
    const float mu = red[0] * (1.0f / 768.0f);
    __syncthreads();
    const float d0 = v0 - mu, d1 = v1 - mu, d2 = v2 - mu;
    red[tid] = d0 * d0 + d1 * d1 + d2 * d2;
    __syncthreads();
    for (int s = 128; s > 0; s >>= 1) {
        if (tid < s) red[tid] += red[tid + s];
        __syncthreads();
    }
    const float rstd = rsqrtf(red[0] * (1.0f / 768.0f) + 1e-5f);
    bf16_t* orow = out + (size_t)t * 768;
    orow[tid]       = (bf16_t)(d0 * rstd * w[tid]);
    orow[tid + 256] = (bf16_t)(d1 * rstd * w[tid + 256]);
    orow[tid + 512] = (bf16_t)(d2 * rstd * w[tid + 512]);
}

// ---------------------------------------------------------------------------
// RoPE + V transpose (qkv now bf16). grid (T/64, NH), block 256.
// ---------------------------------------------------------------------------
__global__ __launch_bounds__(256) void rope_prep(const bf16_t* __restrict__ qkv,
                                                 const float* __restrict__ tab,
                                                 bf16_t* __restrict__ Qb,
                                                 bf16_t* __restrict__ Kb,
                                                 bf16_t* __restrict__ Vt) {
    const int t0 = blockIdx.x * 64, h = blockIdx.y;
    const int tid = threadIdx.x;
    __shared__ bf16_t vt[64][65];   // [d][k], padded row

    #pragma unroll
    for (int it = 0; it < 16; ++it) {
        const int item = it * 256 + tid;
        const int tl = item >> 6;
        const int which = (item >> 5) & 1;   // 0 = Q, 1 = K
        const int i = item & 31;
        const bf16_t* src = qkv + (size_t)(t0 + tl) * 2304 + which * 768 + h * 64;
        const float2 cs = ((const float2*)tab)[(t0 + tl) * 32 + i];
        const float c = cs.x, s = cs.y;
        const float x1 = (float)src[i], x2 = (float)src[i + 32];
        bf16_t* dst = (which ? Kb : Qb) + ((size_t)h * 2048 + t0 + tl) * 64;
        const float sc = which ? 1.0f : 0.125f;   // fold attn scale into Q
        dst[i]      = (bf16_t)((x1 * c - x2 * s) * sc);
        dst[i + 32] = (bf16_t)((x1 * s + x2 * c) * sc);
    }

    #pragma unroll
    for (int pass = 0; pass < 2; ++pass) {
        const int r = pass * 32 + (tid >> 3);   // key row 0..63
        const int c = (tid & 7) * 8;            // d 0..56
        const bf16x8 v = *(const bf16x8*)(qkv + (size_t)(t0 + r) * 2304 + 1536 + h * 64 + c);
        #pragma unroll
        for (int j = 0; j < 8; ++j) vt[c + j][r] = v[j];
    }
    __syncthreads();
    #pragma unroll
    for (int pass = 0; pass < 2; ++pass) {
        const int d = pass * 32 + (tid >> 3);
        const int k8 = (tid & 7) * 8;
        bf16x8 vv;
        #pragma unroll
        for (int j = 0; j < 8; ++j) vv[j] = vt[d][k8 + j];
        *(bf16x8*)(Vt + ((size_t)h * 64 + d) * 2048 + t0 + k8) = vv;
    }
}

// ---------------------------------------------------------------------------
// MFMA flash attention. Block = (64-query tile, head), 256 threads (4 waves).
// K/V for tile kt+1 are loaded into registers while tile kt computes (T14).
// ---------------------------------------------------------------------------
__global__ __launch_bounds__(256) void attn_mfma(const bf16_t* __restrict__ Qb,
                                                 const bf16_t* __restrict__ Kb,
                                                 const bf16_t* __restrict__ Vt,
                                                 bf16_t* __restrict__ y) {
    const int qt = (int)gridDim.x - 1 - (int)blockIdx.x;  // longest blocks first
    const int h  = blockIdx.y;
    const int q0 = qt * 64;
    const int tid = threadIdx.x;
    const int w = tid >> 6, lane = tid & 63;
    const int lg = lane >> 4;       // lane group 0..3
    const int ll = lane & 15;

    __shared__ bf16_t Ks[64 * 64];  // [key][d], swizzled
    __shared__ bf16_t Vs[64 * 64];  // [d][key] (V^T tile), swizzled
    __shared__ bf16_t Ps[64 * 64];  // [q][key], swizzled (per-wave private rows)

    bf16x8 aq0, aq1;
    {
        const bf16_t* qp = Qb + ((size_t)h * 2048 + q0 + w * 16 + ll) * 64 + lg * 8;
        aq0 = *(const bf16x8*)qp;
        aq1 = *(const bf16x8*)(qp + 32);
    }

    f32x4 o[4];
    #pragma unroll
    for (int i = 0; i < 4; ++i) o[i] = (f32x4)(0.0f);
    float m_i[4], l_i[4];
    #pragma unroll
    for (int r = 0; r < 4; ++r) { m_i[r] = -3e38f; l_i[r] = 0.0f; }

    const int srow0 = tid >> 3;          // rows 0..31
    const int srow1 = srow0 + 32;        // rows 32..63
    const int sc16  = tid & 7;           // 16B chunk within 128B row

    const bf16_t* Kbase = Kb + (size_t)h * 2048 * 64;
    const bf16_t* Vbase = Vt + (size_t)h * 64 * 2048;

    bf16x8 pk0, pk1, pv0, pv1;   // prefetched K/V tile
    {
        const bf16_t* kg = Kbase;
        pk0 = *(const bf16x8*)(kg + srow0 * 64 + sc16 * 8);
        pk1 = *(const bf16x8*)(kg + srow1 * 64 + sc16 * 8);
        pv0 = *(const bf16x8*)(Vbase + (size_t)srow0 * 2048 + sc16 * 8);
        pv1 = *(const bf16x8*)(Vbase + (size_t)srow1 * 2048 + sc16 * 8);
    }

    for (int kt = 0; kt <= qt; ++kt) {
        __syncthreads();   // previous tile fully consumed
        *(bf16x8*)((char*)(Ks + srow0 * 64) + ((sc16 * 16) ^ ((srow0 & 7) << 4))) = pk0;
        *(bf16x8*)((char*)(Ks + srow1 * 64) + ((sc16 * 16) ^ ((srow1 & 7) << 4))) = pk1;
        *(bf16x8*)((char*)(Vs + srow0 * 64) + ((sc16 * 16) ^ ((srow0 & 7) << 4))) = pv0;
        *(bf16x8*)((char*)(Vs + srow1 * 64) + ((sc16 * 16) ^ ((srow1 & 7) << 4))) = pv1;
        __syncthreads();

        // prefetch next tile into registers (latency hides under compute)
        if (kt < qt) {
            const bf16_t* kg = Kbase + (size_t)((kt + 1) * 64) * 64;
            pk0 = *(const bf16x8*)(kg + srow0 * 64 + sc16 * 8);
            pk1 = *(const bf16x8*)(kg + srow1 * 64 + sc16 * 8);
            const bf16_t* vg = Vbase + (kt + 1) * 64;
            pv0 = *(const bf16x8*)(vg + (size_t)srow0 * 2048 + sc16 * 8);
            pv1 = *(const bf16x8*)(vg + (size_t)srow1 * 2048 + sc16 * 8);
        }

        // ---- S = (Q*0.125) @ K^T ----
        f32x4 sacc[4];
        #pragma unroll
        for (int kb = 0; kb < 4; ++kb) {
            const int krow = kb * 16 + ll;
            const char* kr = (const char*)(Ks + krow * 64);
            const int sw = (krow & 7) << 4;
            const bf16x8 b0 = *(const bf16x8*)(kr + ((lg * 16) ^ sw));
            const bf16x8 b1 = *(const bf16x8*)(kr + ((64 + lg * 16) ^ sw));
            sacc[kb] = __builtin_amdgcn_mfma_f32_16x16x32_bf16(aq0, b0, (f32x4)(0.0f), 0, 0, 0);
            sacc[kb] = __builtin_amdgcn_mfma_f32_16x16x32_bf16(aq1, b1, sacc[kb], 0, 0, 0);
        }

        // ---- causal mask + online softmax ----
        float sc_[4][4];
        const bool diag = (kt == qt);
        #pragma unroll
        for (int kb = 0; kb < 4; ++kb) {
            #pragma unroll
            for (int r = 0; r < 4; ++r) {
                float v = sacc[kb][r];
                if (diag && (kb * 16 + ll) > (w * 16 + lg * 4 + r)) v = -3e38f;
                sc_[kb][r] = v;
            }
        }
        float rmax[4];
        #pragma unroll
        for (int r = 0; r < 4; ++r)
            rmax[r] = fmaxf(fmaxf(sc_[0][r], sc_[1][r]), fmaxf(sc_[2][r], sc_[3][r]));
        #pragma unroll
        for (int st = 0; st < 4; ++st) {
            const int off = 1 << st;
            #pragma unroll
            for (int r = 0; r < 4; ++r)
                rmax[r] = fmaxf(rmax[r], __shfl_xor(rmax[r], off));
        }
        float alpha[4], rsum[4];
        #pragma unroll
        for (int r = 0; r < 4; ++r) {
            const float mn = fmaxf(m_i[r], rmax[r]);
            alpha[r] = __expf(m_i[r] - mn);
            m_i[r] = mn;
            rsum[r] = 0.0f;
        }
        #pragma unroll
        for (int kb = 0; kb < 4; ++kb) {
            #pragma unroll
            for (int r = 0; r < 4; ++r) {
                const float p = __expf(sc_[kb][r] - m_i[r]);
                sc_[kb][r] = p;
                rsum[r] += p;
            }
        }
        #pragma unroll
        for (int st = 0; st < 4; ++st) {
            const int off = 1 << st;
            #pragma unroll
            for (int r = 0; r < 4; ++r)
                rsum[r] += __shfl_xor(rsum[r], off);
        }
        #pragma unroll
        for (int r = 0; r < 4; ++r) l_i[r] = l_i[r] * alpha[r] + rsum[r];

        // ---- P -> LDS (bf16, swizzled) ----
        #pragma unroll
        for (int r = 0; r < 4; ++r) {
            const int prow = w * 16 + lg * 4 + r;
            char* pb = (char*)(Ps + prow * 64);
            const int sw = (prow & 7) << 4;
            #pragma unroll
            for (int kb = 0; kb < 4; ++kb)
                *(bf16_t*)(pb + (((kb * 16 + ll) * 2) ^ sw)) = (bf16_t)sc_[kb][r];
        }

        // ---- rescale O, then O += P @ V ----
        #pragma unroll
        for (int db = 0; db < 4; ++db)
            #pragma unroll
            for (int r = 0; r < 4; ++r) o[db][r] *= alpha[r];

        #pragma unroll
        for (int ks = 0; ks < 2; ++ks) {
            const int arow = w * 16 + ll;
            const bf16x8 ap = *(const bf16x8*)((const char*)(Ps + arow * 64) +
                                ((ks * 64 + lg * 16) ^ ((arow & 7) << 4)));
            #pragma unroll
            for (int db = 0; db < 4; ++db) {
                const int vrow = db * 16 + ll;
                const bf16x8 bv = *(const bf16x8*)((const char*)(Vs + vrow * 64) +
                                    ((ks * 64 + lg * 16) ^ ((vrow & 7) << 4)));
                o[db] = __builtin_amdgcn_mfma_f32_16x16x32_bf16(ap, bv, o[db], 0, 0, 0);
            }
        }
    }

    #pragma unroll
    for (int r = 0; r < 4; ++r) {
        const float inv = 1.0f / l_i[r];
        bf16_t* yo = y + (size_t)(q0 + w * 16 + lg * 4 + r) * 768 + h * 64 + ll;
        #pragma unroll
        for (int db = 0; db < 4; ++db)
            yo[db * 16] = (bf16_t)(o[db][r] * inv);
    }
}

// ---------------------------------------------------------------------------
// MFMA NT GEMM: C[M,N] = A[M,K](bf16) * B[N,K](bf16)^T, fp32 accumulate.
// Tile BM x BN. BN=128 -> 256 threads (4 waves); BN=256 -> 512 threads (8
// waves, 2x4). Double-buffered LDS with counted vmcnt. K % 64 == 0.
// FLAGS: 1=bias, 2=residual into C32, 4=GELU, 8=bf16 out,
//        16=unembed mode (XCD-partitioned panel remap)
// ---------------------------------------------------------------------------
template <int FLAGS, int BM, int BN>
__global__ __launch_bounds__((BN == 256) ? 512 : 256)
void gemm_bt(const bf16_t* __restrict__ A,
             const bf16_t* __restrict__ B,
             const float* __restrict__ bias,
             float* __restrict__ C32,
             bf16_t* __restrict__ Cb,
             int M, int N, int K) {
    constexpr bool HAS_BIAS = (FLAGS & 1) != 0;
    constexpr bool HAS_RES  = (FLAGS & 2) != 0;
    constexpr bool HAS_GELU = (FLAGS & 4) != 0;
    constexpr bool OUT_BF16 = (FLAGS & 8) != 0;
    constexpr bool UNEMB    = (FLAGS & 16) != 0;
    constexpr bool WIDE     = (BN == 256);               // 512-thread variant
    constexpr int  WM       = WIDE ? 64 : ((BM == 128) ? 64 : 32);
    constexpr int  MI       = WM / 16;
    constexpr int  NLOADS   = WIDE ? 3 : ((BM == 128) ? 4 : 3);

    __shared__ bf16_t smem[2 * (BM + BN) * 32];
    bf16_t* As0 = smem;
    bf16_t* Bs0 = As0 + BM * 32;
    bf16_t* As1 = Bs0 + BN * 32;
    bf16_t* Bs1 = As1 + BM * 32;

    const int tid = threadIdx.x;
    const int w = tid >> 6, lane = tid & 63;

    int bm, bn;
    if constexpr (UNEMB) {
        // Remap so each XCD owns a contiguous panel range (bid%8 = HW XCD).
        const int bid  = (int)blockIdx.y * (int)gridDim.x + (int)blockIdx.x;
        const int per  = ((int)gridDim.x * (int)gridDim.y) >> 3;   // blocks/XCD
        const int nid  = (bid & 7) * per + (bid >> 3);
        bm = (nid & 15) * BM;          // M-tile fast: 16 blocks share a panel
        bn = (nid >> 4) * BN;
    } else {
        bm = blockIdx.y * BM;
        bn = blockIdx.x * BN;
    }
    int wm, wn;
    if constexpr (WIDE) { wm = (w >> 2) * 64; wn = (w & 3) * 64; }
    else                { wm = (w >> 1) * WM; wn = (w & 1) * 64; }

    const int sc = (lane & 3) * 8;
    // B staging
    const int srB = w * 32 + (lane >> 2);                 // WIDE: 8w x 32 = 256
    const bf16_t* gB0 = B + (size_t)(bn + srB) * K + sc;
    const bf16_t* gB1 = gB0 + (size_t)16 * K;
    const int ldsB = (w * 32) * 32;
    // A staging
    const int srA = (!WIDE && BM == 128) ? srB : (w * 16 + (lane >> 2));
    const bf16_t* gA0 = A + (size_t)(bm + srA) * K + sc;
    const bf16_t* gA1 = gA0 + (size_t)16 * K;             // only for narrow BM=128
    const int ldsA = ((!WIDE && BM == 128) ? (w * 32) : (w * 16)) * 32;

    const int mrow  = lane & 15;
    const int khalf = (lane >> 4) * 8;

    f32x4 acc[MI][4];
    #pragma unroll
    for (int i = 0; i < MI; ++i)
        #pragma unroll
        for (int j = 0; j < 4; ++j) acc[i][j] = (f32x4)(0.0f);

    auto stage = [&](bf16_t* Ap, bf16_t* Bp, int kk) {
        gl_lds16(gA0 + kk, Ap + ldsA);
        if constexpr (!WIDE && BM == 128) gl_lds16(gA1 + kk, Ap + ldsA + 16 * 32);
        gl_lds16(gB0 + kk, Bp + ldsB);
        gl_lds16(gB1 + kk, Bp + ldsB + 16 * 32);
    };
    auto compute = [&](const bf16_t* Ap, const bf16_t* Bp) {
        bf16x8 af[MI], bfr[4];
        #pragma unroll
        for (int i = 0; i < MI; ++i)
            af[i] = *(const bf16x8*)(Ap + (wm + i * 16 + mrow) * 32 + khalf);
        #pragma unroll
        for (int j = 0; j < 4; ++j)
            bfr[j] = *(const bf16x8*)(Bp + (wn + j * 16 + mrow) * 32 + khalf);
        #pragma unroll
        for (int i = 0; i < MI; ++i)
            #pragma unroll
            for (int j = 0; j < 4; ++j)
                acc[i][j] = __builtin_amdgcn_mfma_f32_16x16x32_bf16(
                    af[i], bfr[j], acc[i][j], 0, 0, 0);
    };

    stage(As0, Bs0, 0);
    for (int k0 = 0; k0 < K; k0 += 64) {
        // phase A: compute buf0 @ k0, prefetch buf1 @ k0+32 (always valid)
        stage(As1, Bs1, k0 + 32);
        wait_vm<NLOADS>();
        __builtin_amdgcn_s_barrier();
        __builtin_amdgcn_sched_barrier(0);
        compute(As0, Bs0);
        __builtin_amdgcn_sched_barrier(0);
        __builtin_amdgcn_s_barrier();
        // phase B: compute buf1 @ k0+32, prefetch buf0 @ k0+64
        const bool more = (k0 + 64) < K;
        if (more) stage(As0, Bs0, k0 + 64);
        if (more) wait_vm<NLOADS>(); else wait_vm<0>();
        __builtin_amdgcn_s_barrier();
        __builtin_amdgcn_sched_barrier(0);
        compute(As1, Bs1);
        __builtin_amdgcn_sched_barrier(0);
        __builtin_amdgcn_s_barrier();
    }

    const int ccol = lane & 15;
    const int crow = (lane >> 4) * 4;
    #pragma unroll
    for (int i = 0; i < MI; ++i) {
        #pragma unroll
        for (int j = 0; j < 4; ++j) {
            const int col = bn + wn + j * 16 + ccol;
            #pragma unroll
            for (int r = 0; r < 4; ++r) {
                const int row = bm + wm + i * 16 + crow + r;
                float v = acc[i][j][r];
                if constexpr (HAS_BIAS) v += bias[col];
                if constexpr (HAS_GELU) v = 0.5f * v * (1.0f + erff(v * 0.70710678f));
                const size_t off = (size_t)row * N + col;
                if constexpr (HAS_RES) v += C32[off];
                if constexpr (OUT_BF16) Cb[off] = (bf16_t)v;
                else C32[off] = v;
            }
        }
    }
}

// ---------------------------------------------------------------------------
// Host launch
// ---------------------------------------------------------------------------
extern "C" void kernel_launch(void* const* d_in, const int* in_sizes, int n_in,
                              void* d_out, int out_size, void* d_ws, size_t ws_size,
                              hipStream_t stream) {
    const int T = 2048, D = 768, NH = 12, L = 4, V = 32000;
    const int D3 = 3 * D, D4 = 4 * D;

    const int*   idx        = (const int*)d_in[0];
    const float* wte        = (const float*)d_in[1];
    const float* ln1_w      = (const float*)d_in[2];
    const float* attn_w     = (const float*)d_in[3];
    const float* attnproj_w = (const float*)d_in[4];
    const float* ln2_w      = (const float*)d_in[5];
    const float* fc_w       = (const float*)d_in[6];
    const float* fc_b       = (const float*)d_in[7];
    const float* proj_w     = (const float*)d_in[8];
    const float* proj_b     = (const float*)d_in[9];
    const float* lnf_w      = (const float*)d_in[10];
    const float* unemb_b    = (const float*)d_in[11];
    float* out = (float*)d_out;

    // workspace layout (~129 MB of 1 GB)
    char* p = (char*)d_ws;
    float*  X      = (float*)p;   p += (size_t)T * D * 4;        // 6.3 MB
    bf16_t* Hb     = (bf16_t*)p;  p += (size_t)T * D * 2;        // 3.1 MB
    bf16_t* QKVb   = (bf16_t*)p;                                  // 9.4 MB (union)
    bf16_t* Mb     = QKVb;        p += (size_t)T * D4 * 2;       // 12.6 MB span
    bf16_t* wte_b  = (bf16_t*)p;  p += (size_t)V * D * 2;        // 49.2 MB
    bf16_t* w_attn = (bf16_t*)p;  p += (size_t)L * D3 * D * 2;   // 14.2 MB
    bf16_t* w_apr  = (bf16_t*)p;  p += (size_t)L * D * D * 2;    //  4.7 MB
    bf16_t* w_fc   = (bf16_t*)p;  p += (size_t)L * D4 * D * 2;   // 18.9 MB
    bf16_t* w_proj = (bf16_t*)p;  p += (size_t)L * D * D4 * 2;   // 18.9 MB
    float*  rtab   = (float*)p;   p += (size_t)T * 32 * 2 * 4;   // 0.5 MB

    // Q/K/V^T bf16 buffers overlay wte_b (dead until after the layer loop)
    bf16_t* Qb  = wte_b;
    bf16_t* Kbf = Qb  + (size_t)NH * T * 64;
    bf16_t* Vtg = Kbf + (size_t)NH * T * 64;

    embed_kernel<<<T, 256, 0, stream>>>(idx, wte, X);
    rope_table<<<T * 32 / 256, 256, 0, stream>>>(rtab);

    // all-layer weight casts, one launch
    const int na = L * D3 * D / 4, nb = L * D * D / 4;
    const int nc = L * D4 * D / 4, nd = L * D * D4 / 4;
    const int ntot = na + nb + nc + nd;
    cvt4_kernel<<<(ntot + 255) / 256, 256, 0, stream>>>(
        attn_w, attnproj_w, fc_w, proj_w,
        w_attn, w_apr, w_fc, w_proj, na, nb, nc, nd);

    for (int l = 0; l < L; ++l) {
        // h = LN1(x)  (bf16)
        ln_kernel<<<T, 256, 0, stream>>>(X, ln1_w + (size_t)l * D, Hb);
        // qkv = h @ attn_w^T  (bf16 out)
        gemm_bt<8, 128, 128><<<dim3(D3 / 128, T / 128), 256, 0, stream>>>(
            Hb, w_attn + (size_t)l * D3 * D, nullptr, nullptr, QKVb, T, D3, D);
        // RoPE + V transpose (bf16 in)
        rope_prep<<<dim3(T / 64, NH), 256, 0, stream>>>(QKVb, rtab, Qb, Kbf, Vtg);
        // y = attn(q,k,v)  (bf16 into Hb)
        attn_mfma<<<dim3(T / 64, NH), 256, 0, stream>>>(Qb, Kbf, Vtg, Hb);
        // x += y @ attnproj_w^T
        gemm_bt<2, 64, 128><<<dim3(D / 128, T / 64), 256, 0, stream>>>(
            Hb, w_apr + (size_t)l * D * D, nullptr, X, nullptr, T, D, D);
        // h = LN2(x)
        ln_kernel<<<T, 256, 0, stream>>>(X, ln2_w + (size_t)l * D, Hb);
        // m = gelu(h @ fc_w^T + fc_b)  (bf16 out)
        gemm_bt<13, 128, 128><<<dim3(D4 / 128, T / 128), 256, 0, stream>>>(
            Hb, w_fc + (size_t)l * D4 * D, fc_b + (size_t)l * D4, nullptr, Mb, T, D4, D);
        // x += m @ proj_w^T + proj_b
        gemm_bt<3, 64, 128><<<dim3(D / 128, T / 64), 256, 0, stream>>>(
            Mb, w_proj + (size_t)l * D * D4, proj_b + (size_t)l * D, X, nullptr, T, D, D4);
    }

    // hf = LN(x); logits = hf @ wte^T + unemb_b  (fp32 out)
    ln_kernel<<<T, 256, 0, stream>>>(X, lnf_w, Hb);
    {
        const int n4 = V * D / 4;   // deferred: wte_b region was reused above
        cvt_kernel<<<(n4 + 255) / 256, 256, 0, stream>>>(wte, wte_b, n4);
    }
    // unembed: 128x256 tile, 512 threads, XCD-partitioned remap
    gemm_bt<17, 128, 256><<<dim3(T / 128, V / 256), 512, 0, stream>>>(
        Hb, wte_b, unemb_b, out, nullptr, T, V, D);
}

// Round 7
// 1213.666 us; speedup vs baseline: 1.3041x; 1.0154x over previous
//
#include <hip/hip_runtime.h>
#include <hip/hip_bf16.h>

typedef __bf16 bf16_t;
typedef __bf16 bf16x8 __attribute__((ext_vector_type(8)));
typedef __bf16 bf16x4 __attribute__((ext_vector_type(4)));
typedef float  f32x4  __attribute__((ext_vector_type(4)));

// async global->LDS, 16B per lane. LDS dest = wave-uniform base + lane*16.
__device__ __forceinline__ void gl_lds16(const void* g, void* l) {
    __builtin_amdgcn_global_load_lds(
        (__attribute__((address_space(1))) void*)g,
        (__attribute__((address_space(3))) void*)l, 16, 0, 0);
}

template <int N>
__device__ __forceinline__ void wait_vm() {
    if constexpr (N == 0)      asm volatile("s_waitcnt vmcnt(0)" ::: "memory");
    else if constexpr (N == 3) asm volatile("s_waitcnt vmcnt(3)" ::: "memory");
    else                       asm volatile("s_waitcnt vmcnt(4)" ::: "memory");
}

// ---------------------------------------------------------------------------
// fp32 -> bf16 cast, vectorized (n must be multiple of 4)
// ---------------------------------------------------------------------------
__global__ void cvt_kernel(const float* __restrict__ in, bf16_t* __restrict__ out,
                           int n4) {
    const int i = blockIdx.x * 256 + threadIdx.x;
    if (i < n4) {
        const float4 v = ((const float4*)in)[i];
        bf16x4 o;
        o.x = (bf16_t)v.x; o.y = (bf16_t)v.y; o.z = (bf16_t)v.z; o.w = (bf16_t)v.w;
        ((bf16x4*)out)[i] = o;
    }
}

// 4 segments in one launch (all-layer weight casts, hoisted out of the loop)
__global__ void cvt4_kernel(const float* __restrict__ s0, const float* __restrict__ s1,
                            const float* __restrict__ s2, const float* __restrict__ s3,
                            bf16_t* __restrict__ d0, bf16_t* __restrict__ d1,
                            bf16_t* __restrict__ d2, bf16_t* __restrict__ d3,
                            int n0, int n1, int n2, int n3) {
    int j = blockIdx.x * 256 + threadIdx.x;
    const float* s; bf16_t* d;
    if (j < n0) { s = s0; d = d0; }
    else {
        j -= n0;
        if (j < n1) { s = s1; d = d1; }
        else {
            j -= n1;
            if (j < n2) { s = s2; d = d2; }
            else {
                j -= n2;
                if (j >= n3) return;
                s = s3; d = d3;
            }
        }
    }
    const float4 v = ((const float4*)s)[j];
    bf16x4 o;
    o.x = (bf16_t)v.x; o.y = (bf16_t)v.y; o.z = (bf16_t)v.z; o.w = (bf16_t)v.w;
    ((bf16x4*)d)[j] = o;
}

// ---------------------------------------------------------------------------
// RoPE cos/sin table: tab[t*32+i] = {cos, sin}(t * 10000^(-i/32))
// ---------------------------------------------------------------------------
__global__ void rope_table(float* __restrict__ tab) {
    const int i = blockIdx.x * 256 + threadIdx.x;   // T*32 items
    const int t = i >> 5, f = i & 31;
    const float inv_freq = __powf(10000.0f, -(float)f * (1.0f / 32.0f));
    const float ang = (float)t * inv_freq;
    float s, c;
    __sincosf(ang, &s, &c);
    tab[2 * i]     = c;
    tab[2 * i + 1] = s;
}

// ---------------------------------------------------------------------------
// Embedding gather: x[t,:] = wte[idx[t],:]  (fp32, float4)
// ---------------------------------------------------------------------------
__global__ void embed_kernel(const int* __restrict__ idx,
                             const float* __restrict__ wte,
                             float* __restrict__ x) {
    const int t = blockIdx.x;
    const int row = idx[t];
    const float4* w = (const float4*)(wte + (size_t)row * 768);
    float4* o = (float4*)(x + (size_t)t * 768);
    if (threadIdx.x < 192) o[threadIdx.x] = w[threadIdx.x];
}

// ---------------------------------------------------------------------------
// LayerNorm: out(bf16) = (x - mu) * rsqrt(var + eps) * w      D = 768
// ---------------------------------------------------------------------------
__global__ __launch_bounds__(256) void ln_kernel(const float* __restrict__ x,
                                                 const float* __restrict__ w,
                                                 bf16_t* __restrict__ out) {
    const int t = blockIdx.x, tid = threadIdx.x;
    __shared__ float red[256];
    const float* xr = x + (size_t)t * 768;
    const float v0 = xr[tid], v1 = xr[tid + 256], v2 = xr[tid + 512];
    red[tid] = v0 + v1 + v2;
    __syncthreads();
    for (int s = 128; s > 0; s >>= 1) {
        if (tid < s) red[tid] += red[tid + s];
        __syncthreads();
    }
    const float mu = red[0] * (1.0f / 768.0f);
    __syncthreads();
    const float d0 = v0 - mu, d1 = v1 - mu, d2 = v2 - mu;
    red[tid] = d0 * d0 + d1 * d1 + d2 * d2;
    __syncthreads();
    for (int s = 128; s > 0; s >>= 1) {
        if (tid < s) red[tid] += red[tid + s];
        __syncthreads();
    }
    const float rstd = rsqrtf(red[0] * (1.0f / 768.0f) + 1e-5f);
    bf16_t* orow = out + (size_t)t * 768;
    orow[tid]       = (bf16_t)(d0 * rstd * w[tid]);
    orow[tid + 256] = (bf16_t)(d1 * rstd * w[tid + 256]);
    orow[tid + 512] = (bf16_t)(d2 * rstd * w[tid + 512]);
}

// ---------------------------------------------------------------------------
// MFMA flash attention. Block = (64-query tile, head), 256 threads (4 waves).
// K/V for tile kt+1 are loaded into registers while tile kt computes (T14).
// ---------------------------------------------------------------------------
__global__ __launch_bounds__(256) void attn_mfma(const bf16_t* __restrict__ Qb,
                                                 const bf16_t* __restrict__ Kb,
                                                 const bf16_t* __restrict__ Vt,
                                                 bf16_t* __restrict__ y) {
    const int qt = (int)gridDim.x - 1 - (int)blockIdx.x;  // longest blocks first
    const int h  = blockIdx.y;
    const int q0 = qt * 64;
    const int tid = threadIdx.x;
    const int w = tid >> 6, lane = tid & 63;
    const int lg = lane >> 4;       // lane group 0..3
    const int ll = lane & 15;

    __shared__ bf16_t Ks[64 * 64];  // [key][d], swizzled
    __shared__ bf16_t Vs[64 * 64];  // [d][key] (V^T tile), swizzled
    __shared__ bf16_t Ps[64 * 64];  // [q][key], swizzled (per-wave private rows)

    bf16x8 aq0, aq1;
    {
        const bf16_t* qp = Qb + ((size_t)h * 2048 + q0 + w * 16 + ll) * 64 + lg * 8;
        aq0 = *(const bf16x8*)qp;
        aq1 = *(const bf16x8*)(qp + 32);
    }

    f32x4 o[4];
    #pragma unroll
    for (int i = 0; i < 4; ++i) o[i] = (f32x4)(0.0f);
    float m_i[4], l_i[4];
    #pragma unroll
    for (int r = 0; r < 4; ++r) { m_i[r] = -3e38f; l_i[r] = 0.0f; }

    const int srow0 = tid >> 3;          // rows 0..31
    const int srow1 = srow0 + 32;        // rows 32..63
    const int sc16  = tid & 7;           // 16B chunk within 128B row

    const bf16_t* Kbase = Kb + (size_t)h * 2048 * 64;
    const bf16_t* Vbase = Vt + (size_t)h * 64 * 2048;

    bf16x8 pk0, pk1, pv0, pv1;   // prefetched K/V tile
    {
        const bf16_t* kg = Kbase;
        pk0 = *(const bf16x8*)(kg + srow0 * 64 + sc16 * 8);
        pk1 = *(const bf16x8*)(kg + srow1 * 64 + sc16 * 8);
        pv0 = *(const bf16x8*)(Vbase + (size_t)srow0 * 2048 + sc16 * 8);
        pv1 = *(const bf16x8*)(Vbase + (size_t)srow1 * 2048 + sc16 * 8);
    }

    for (int kt = 0; kt <= qt; ++kt) {
        __syncthreads();   // previous tile fully consumed
        *(bf16x8*)((char*)(Ks + srow0 * 64) + ((sc16 * 16) ^ ((srow0 & 7) << 4))) = pk0;
        *(bf16x8*)((char*)(Ks + srow1 * 64) + ((sc16 * 16) ^ ((srow1 & 7) << 4))) = pk1;
        *(bf16x8*)((char*)(Vs + srow0 * 64) + ((sc16 * 16) ^ ((srow0 & 7) << 4))) = pv0;
        *(bf16x8*)((char*)(Vs + srow1 * 64) + ((sc16 * 16) ^ ((srow1 & 7) << 4))) = pv1;
        __syncthreads();

        // prefetch next tile into registers (latency hides under compute)
        if (kt < qt) {
            const bf16_t* kg = Kbase + (size_t)((kt + 1) * 64) * 64;
            pk0 = *(const bf16x8*)(kg + srow0 * 64 + sc16 * 8);
            pk1 = *(const bf16x8*)(kg + srow1 * 64 + sc16 * 8);
            const bf16_t* vg = Vbase + (kt + 1) * 64;
            pv0 = *(const bf16x8*)(vg + (size_t)srow0 * 2048 + sc16 * 8);
            pv1 = *(const bf16x8*)(vg + (size_t)srow1 * 2048 + sc16 * 8);
        }

        // ---- S = (Q*0.125) @ K^T ----
        f32x4 sacc[4];
        #pragma unroll
        for (int kb = 0; kb < 4; ++kb) {
            const int krow = kb * 16 + ll;
            const char* kr = (const char*)(Ks + krow * 64);
            const int sw = (krow & 7) << 4;
            const bf16x8 b0 = *(const bf16x8*)(kr + ((lg * 16) ^ sw));
            const bf16x8 b1 = *(const bf16x8*)(kr + ((64 + lg * 16) ^ sw));
            sacc[kb] = __builtin_amdgcn_mfma_f32_16x16x32_bf16(aq0, b0, (f32x4)(0.0f), 0, 0, 0);
            sacc[kb] = __builtin_amdgcn_mfma_f32_16x16x32_bf16(aq1, b1, sacc[kb], 0, 0, 0);
        }

        // ---- causal mask + online softmax ----
        float sc_[4][4];
        const bool diag = (kt == qt);
        #pragma unroll
        for (int kb = 0; kb < 4; ++kb) {
            #pragma unroll
            for (int r = 0; r < 4; ++r) {
                float v = sacc[kb][r];
                if (diag && (kb * 16 + ll) > (w * 16 + lg * 4 + r)) v = -3e38f;
                sc_[kb][r] = v;
            }
        }
        float rmax[4];
        #pragma unroll
        for (int r = 0; r < 4; ++r)
            rmax[r] = fmaxf(fmaxf(sc_[0][r], sc_[1][r]), fmaxf(sc_[2][r], sc_[3][r]));
        #pragma unroll
        for (int st = 0; st < 4; ++st) {
            const int off = 1 << st;
            #pragma unroll
            for (int r = 0; r < 4; ++r)
                rmax[r] = fmaxf(rmax[r], __shfl_xor(rmax[r], off));
        }
        float alpha[4], rsum[4];
        #pragma unroll
        for (int r = 0; r < 4; ++r) {
            const float mn = fmaxf(m_i[r], rmax[r]);
            alpha[r] = __expf(m_i[r] - mn);
            m_i[r] = mn;
            rsum[r] = 0.0f;
        }
        #pragma unroll
        for (int kb = 0; kb < 4; ++kb) {
            #pragma unroll
            for (int r = 0; r < 4; ++r) {
                const float p = __expf(sc_[kb][r] - m_i[r]);
                sc_[kb][r] = p;
                rsum[r] += p;
            }
        }
        #pragma unroll
        for (int st = 0; st < 4; ++st) {
            const int off = 1 << st;
            #pragma unroll
            for (int r = 0; r < 4; ++r)
                rsum[r] += __shfl_xor(rsum[r], off);
        }
        #pragma unroll
        for (int r = 0; r < 4; ++r) l_i[r] = l_i[r] * alpha[r] + rsum[r];

        // ---- P -> LDS (bf16, swizzled) ----
        #pragma unroll
        for (int r = 0; r < 4; ++r) {
            const int prow = w * 16 + lg * 4 + r;
            char* pb = (char*)(Ps + prow * 64);
            const int sw = (prow & 7) << 4;
            #pragma unroll
            for (int kb = 0; kb < 4; ++kb)
                *(bf16_t*)(pb + (((kb * 16 + ll) * 2) ^ sw)) = (bf16_t)sc_[kb][r];
        }

        // ---- rescale O, then O += P @ V ----
        #pragma unroll
        for (int db = 0; db < 4; ++db)
            #pragma unroll
            for (int r = 0; r < 4; ++r) o[db][r] *= alpha[r];

        #pragma unroll
        for (int ks = 0; ks < 2; ++ks) {
            const int arow = w * 16 + ll;
            const bf16x8 ap = *(const bf16x8*)((const char*)(Ps + arow * 64) +
                                ((ks * 64 + lg * 16) ^ ((arow & 7) << 4)));
            #pragma unroll
            for (int db = 0; db < 4; ++db) {
                const int vrow = db * 16 + ll;
                const bf16x8 bv = *(const bf16x8*)((const char*)(Vs + vrow * 64) +
                                    ((ks * 64 + lg * 16) ^ ((vrow & 7) << 4)));
                o[db] = __builtin_amdgcn_mfma_f32_16x16x32_bf16(ap, bv, o[db], 0, 0, 0);
            }
        }
    }

    #pragma unroll
    for (int r = 0; r < 4; ++r) {
        const float inv = 1.0f / l_i[r];
        bf16_t* yo = y + (size_t)(q0 + w * 16 + lg * 4 + r) * 768 + h * 64 + ll;
        #pragma unroll
        for (int db = 0; db < 4; ++db)
            yo[db * 16] = (bf16_t)(o[db][r] * inv);
    }
}

// ---------------------------------------------------------------------------
// MFMA NT GEMM: C[M,N] = A[M,K](bf16) * B[N,K](bf16)^T, fp32 accumulate.
// Tile BM x BN. BN=128 -> 256 threads (4 waves); BN=256 -> 512 threads (8
// waves, 2x4). Double-buffered LDS with counted vmcnt. K % 64 == 0.
// FLAGS: 1=bias, 2=residual into C32, 4=GELU, 8=bf16 out,
//        16=unembed mode (XCD-partitioned panel remap),
//        32=QKV mode (fused RoPE + Q-scale + V-transpose epilogue)
// ---------------------------------------------------------------------------
template <int FLAGS, int BM, int BN>
__global__ __launch_bounds__((BN == 256) ? 512 : 256)
void gemm_bt(const bf16_t* __restrict__ A,
             const bf16_t* __restrict__ B,
             const float* __restrict__ bias,
             float* __restrict__ C32,
             bf16_t* __restrict__ Cb,
             const float* __restrict__ rt,
             bf16_t* __restrict__ Qd,
             bf16_t* __restrict__ Kd,
             bf16_t* __restrict__ Vd,
             int M, int N, int K) {
    constexpr bool HAS_BIAS = (FLAGS & 1) != 0;
    constexpr bool HAS_RES  = (FLAGS & 2) != 0;
    constexpr bool HAS_GELU = (FLAGS & 4) != 0;
    constexpr bool OUT_BF16 = (FLAGS & 8) != 0;
    constexpr bool UNEMB    = (FLAGS & 16) != 0;
    constexpr bool QKV      = (FLAGS & 32) != 0;
    constexpr bool WIDE     = (BN == 256);               // 512-thread variant
    constexpr int  WM       = WIDE ? 64 : ((BM == 128) ? 64 : 32);
    constexpr int  MI       = WM / 16;
    constexpr int  NLOADS   = WIDE ? 3 : ((BM == 128) ? 4 : 3);

    __shared__ bf16_t smem[2 * (BM + BN) * 32];
    bf16_t* As0 = smem;
    bf16_t* Bs0 = As0 + BM * 32;
    bf16_t* As1 = Bs0 + BN * 32;
    bf16_t* Bs1 = As1 + BM * 32;

    const int tid = threadIdx.x;
    const int w = tid >> 6, lane = tid & 63;

    int bm, bn;
    if constexpr (UNEMB) {
        // Remap so each XCD owns a contiguous panel range (bid%8 = HW XCD).
        const int bid  = (int)blockIdx.y * (int)gridDim.x + (int)blockIdx.x;
        const int per  = ((int)gridDim.x * (int)gridDim.y) >> 3;   // blocks/XCD
        const int nid  = (bid & 7) * per + (bid >> 3);
        bm = (nid & 15) * BM;          // M-tile fast: 16 blocks share a panel
        bn = (nid >> 4) * BN;
    } else {
        bm = blockIdx.y * BM;
        bn = blockIdx.x * BN;
    }
    int wm, wn;
    if constexpr (WIDE) { wm = (w >> 2) * 64; wn = (w & 3) * 64; }
    else                { wm = (w >> 1) * WM; wn = (w & 1) * 64; }

    const int sc = (lane & 3) * 8;
    // B staging
    const int srB = w * 32 + (lane >> 2);                 // WIDE: 8w x 32 = 256
    const bf16_t* gB0 = B + (size_t)(bn + srB) * K + sc;
    const bf16_t* gB1 = gB0 + (size_t)16 * K;
    const int ldsB = (w * 32) * 32;
    // A staging
    const int srA = (!WIDE && BM == 128) ? srB : (w * 16 + (lane >> 2));
    const bf16_t* gA0 = A + (size_t)(bm + srA) * K + sc;
    const bf16_t* gA1 = gA0 + (size_t)16 * K;             // only for narrow BM=128
    const int ldsA = ((!WIDE && BM == 128) ? (w * 32) : (w * 16)) * 32;

    const int mrow  = lane & 15;
    const int khalf = (lane >> 4) * 8;

    f32x4 acc[MI][4];
    #pragma unroll
    for (int i = 0; i < MI; ++i)
        #pragma unroll
        for (int j = 0; j < 4; ++j) acc[i][j] = (f32x4)(0.0f);

    auto stage = [&](bf16_t* Ap, bf16_t* Bp, int kk) {
        gl_lds16(gA0 + kk, Ap + ldsA);
        if constexpr (!WIDE && BM == 128) gl_lds16(gA1 + kk, Ap + ldsA + 16 * 32);
        gl_lds16(gB0 + kk, Bp + ldsB);
        gl_lds16(gB1 + kk, Bp + ldsB + 16 * 32);
    };
    auto compute = [&](const bf16_t* Ap, const bf16_t* Bp) {
        bf16x8 af[MI], bfr[4];
        #pragma unroll
        for (int i = 0; i < MI; ++i)
            af[i] = *(const bf16x8*)(Ap + (wm + i * 16 + mrow) * 32 + khalf);
        #pragma unroll
        for (int j = 0; j < 4; ++j)
            bfr[j] = *(const bf16x8*)(Bp + (wn + j * 16 + mrow) * 32 + khalf);
        #pragma unroll
        for (int i = 0; i < MI; ++i)
            #pragma unroll
            for (int j = 0; j < 4; ++j)
                acc[i][j] = __builtin_amdgcn_mfma_f32_16x16x32_bf16(
                    af[i], bfr[j], acc[i][j], 0, 0, 0);
    };

    stage(As0, Bs0, 0);
    for (int k0 = 0; k0 < K; k0 += 64) {
        // phase A: compute buf0 @ k0, prefetch buf1 @ k0+32 (always valid)
        stage(As1, Bs1, k0 + 32);
        wait_vm<NLOADS>();
        __builtin_amdgcn_s_barrier();
        __builtin_amdgcn_sched_barrier(0);
        compute(As0, Bs0);
        __builtin_amdgcn_sched_barrier(0);
        __builtin_amdgcn_s_barrier();
        // phase B: compute buf1 @ k0+32, prefetch buf0 @ k0+64
        const bool more = (k0 + 64) < K;
        if (more) stage(As0, Bs0, k0 + 64);
        if (more) wait_vm<NLOADS>(); else wait_vm<0>();
        __builtin_amdgcn_s_barrier();
        __builtin_amdgcn_sched_barrier(0);
        compute(As1, Bs1);
        __builtin_amdgcn_sched_barrier(0);
        __builtin_amdgcn_s_barrier();
    }

    const int ccol = lane & 15;
    const int crow = (lane >> 4) * 4;

    if constexpr (QKV) {
        // fused epilogue: col0 = 64-aligned -> one (which, head) per wave.
        // C/D layout: col = wn + j*16 + ccol, row = wm + i*16 + crow + r.
        // d = j*16 + ccol in [0,64); RoPE pairs (d, d+32) = (j, j+2).
        const int col0  = bn + wn;
        const int which = col0 / 768;          // 0=Q 1=K 2=V (wave-uniform)
        const int hh    = (col0 % 768) >> 6;
        #pragma unroll
        for (int i = 0; i < MI; ++i) {
            const int row0 = bm + wm + i * 16 + crow;   // t base (4 rows)
            if (which == 2) {
                // V^T: Vd[(h*64+d)*2048 + t], 4 consecutive t -> bf16x4
                #pragma unroll
                for (int j = 0; j < 4; ++j) {
                    const int d = j * 16 + ccol;
                    bf16x4 v4;
                    #pragma unroll
                    for (int r = 0; r < 4; ++r) v4[r] = (bf16_t)acc[i][j][r];
                    *(bf16x4*)(Vd + (size_t)(hh * 64 + d) * 2048 + row0) = v4;
                }
            } else {
                bf16_t* dst0 = (which ? Kd : Qd) + (size_t)hh * 2048 * 64;
                const float scq = which ? 1.0f : 0.125f;  // attn scale into Q
                #pragma unroll
                for (int j = 0; j < 2; ++j) {
                    const int d = j * 16 + ccol;          // 0..31 = freq index
                    #pragma unroll
                    for (int r = 0; r < 4; ++r) {
                        const int t = row0 + r;
                        const float2 cs = ((const float2*)rt)[t * 32 + d];
                        const float x1 = acc[i][j][r], x2 = acc[i][j + 2][r];
                        bf16_t* dp = dst0 + (size_t)t * 64 + d;
                        dp[0]  = (bf16_t)((x1 * cs.x - x2 * cs.y) * scq);
                        dp[32] = (bf16_t)((x1 * cs.y + x2 * cs.x) * scq);
                    }
                }
            }
        }
        return;
    }

    #pragma unroll
    for (int i = 0; i < MI; ++i) {
        #pragma unroll
        for (int j = 0; j < 4; ++j) {
            const int col = bn + wn + j * 16 + ccol;
            #pragma unroll
            for (int r = 0; r < 4; ++r) {
                const int row = bm + wm + i * 16 + crow + r;
                float v = acc[i][j][r];
                if constexpr (HAS_BIAS) v += bias[col];
                if constexpr (HAS_GELU) v = 0.5f * v * (1.0f + erff(v * 0.70710678f));
                const size_t off = (size_t)row * N + col;
                if constexpr (HAS_RES) v += C32[off];
                if constexpr (OUT_BF16) Cb[off] = (bf16_t)v;
                else C32[off] = v;
            }
        }
    }
}

// ---------------------------------------------------------------------------
// Host launch
// ---------------------------------------------------------------------------
extern "C" void kernel_launch(void* const* d_in, const int* in_sizes, int n_in,
                              void* d_out, int out_size, void* d_ws, size_t ws_size,
                              hipStream_t stream) {
    const int T = 2048, D = 768, NH = 12, L = 4, V = 32000;
    const int D3 = 3 * D, D4 = 4 * D;

    const int*   idx        = (const int*)d_in[0];
    const float* wte        = (const float*)d_in[1];
    const float* ln1_w      = (const float*)d_in[2];
    const float* attn_w     = (const float*)d_in[3];
    const float* attnproj_w = (const float*)d_in[4];
    const float* ln2_w      = (const float*)d_in[5];
    const float* fc_w       = (const float*)d_in[6];
    const float* fc_b       = (const float*)d_in[7];
    const float* proj_w     = (const float*)d_in[8];
    const float* proj_b     = (const float*)d_in[9];
    const float* lnf_w      = (const float*)d_in[10];
    const float* unemb_b    = (const float*)d_in[11];
    float* out = (float*)d_out;

    // workspace layout (~129 MB of 1 GB)
    char* p = (char*)d_ws;
    float*  X      = (float*)p;   p += (size_t)T * D * 4;        // 6.3 MB
    bf16_t* Hb     = (bf16_t*)p;  p += (size_t)T * D * 2;        // 3.1 MB
    bf16_t* Mb     = (bf16_t*)p;  p += (size_t)T * D4 * 2;       // 12.6 MB
    bf16_t* wte_b  = (bf16_t*)p;  p += (size_t)V * D * 2;        // 49.2 MB
    bf16_t* w_attn = (bf16_t*)p;  p += (size_t)L * D3 * D * 2;   // 14.2 MB
    bf16_t* w_apr  = (bf16_t*)p;  p += (size_t)L * D * D * 2;    //  4.7 MB
    bf16_t* w_fc   = (bf16_t*)p;  p += (size_t)L * D4 * D * 2;   // 18.9 MB
    bf16_t* w_proj = (bf16_t*)p;  p += (size_t)L * D * D4 * 2;   // 18.9 MB
    float*  rtab   = (float*)p;   p += (size_t)T * 32 * 2 * 4;   // 0.5 MB

    // Q/K/V^T bf16 buffers overlay wte_b (dead until after the layer loop)
    bf16_t* Qb  = wte_b;
    bf16_t* Kbf = Qb  + (size_t)NH * T * 64;
    bf16_t* Vtg = Kbf + (size_t)NH * T * 64;

    embed_kernel<<<T, 256, 0, stream>>>(idx, wte, X);
    rope_table<<<T * 32 / 256, 256, 0, stream>>>(rtab);

    // all-layer weight casts, one launch
    const int na = L * D3 * D / 4, nb = L * D * D / 4;
    const int nc = L * D4 * D / 4, nd = L * D * D4 / 4;
    const int ntot = na + nb + nc + nd;
    cvt4_kernel<<<(ntot + 255) / 256, 256, 0, stream>>>(
        attn_w, attnproj_w, fc_w, proj_w,
        w_attn, w_apr, w_fc, w_proj, na, nb, nc, nd);

    for (int l = 0; l < L; ++l) {
        // h = LN1(x)  (bf16)
        ln_kernel<<<T, 256, 0, stream>>>(X, ln1_w + (size_t)l * D, Hb);
        // qkv GEMM with fused RoPE/scale/V-transpose epilogue
        gemm_bt<32, 128, 128><<<dim3(D3 / 128, T / 128), 256, 0, stream>>>(
            Hb, w_attn + (size_t)l * D3 * D, nullptr, nullptr, nullptr,
            rtab, Qb, Kbf, Vtg, T, D3, D);
        // y = attn(q,k,v)  (bf16 into Hb)
        attn_mfma<<<dim3(T / 64, NH), 256, 0, stream>>>(Qb, Kbf, Vtg, Hb);
        // x += y @ attnproj_w^T
        gemm_bt<2, 64, 128><<<dim3(D / 128, T / 64), 256, 0, stream>>>(
            Hb, w_apr + (size_t)l * D * D, nullptr, X, nullptr,
            nullptr, nullptr, nullptr, nullptr, T, D, D);
        // h = LN2(x)
        ln_kernel<<<T, 256, 0, stream>>>(X, ln2_w + (size_t)l * D, Hb);
        // m = gelu(h @ fc_w^T + fc_b)  (bf16 out)
        gemm_bt<13, 128, 128><<<dim3(D4 / 128, T / 128), 256, 0, stream>>>(
            Hb, w_fc + (size_t)l * D4 * D, fc_b + (size_t)l * D4, nullptr, Mb,
            nullptr, nullptr, nullptr, nullptr, T, D4, D);
        // x += m @ proj_w^T + proj_b
        gemm_bt<3, 64, 128><<<dim3(D / 128, T / 64), 256, 0, stream>>>(
            Mb, w_proj + (size_t)l * D * D4, proj_b + (size_t)l * D, X, nullptr,
            nullptr, nullptr, nullptr, nullptr, T, D, D4);
    }

    // hf = LN(x); logits = hf @ wte^T + unemb_b  (fp32 out)
    ln_kernel<<<T, 256, 0, stream>>>(X, lnf_w, Hb);
    {
        const int n4 = V * D / 4;   // deferred: wte_b region was reused above
        cvt_kernel<<<(n4 + 255) / 256, 256, 0, stream>>>(wte, wte_b, n4);
    }
    // unembed: 128x256 tile, 512 threads, XCD-partitioned remap
    gemm_bt<17, 128, 256><<<dim3(T / 128, V / 256), 512, 0, stream>>>(
        Hb, wte_b, unemb_b, out, nullptr,
        nullptr, nullptr, nullptr, nullptr, T, V, D);
}